// Round 4
// baseline (635.962 us; speedup 1.0000x reference)
//
#include <hip/hip_runtime.h>
#include <math.h>

#define DD 128
typedef unsigned int   u32;
typedef unsigned short u16;
typedef short bf16x8 __attribute__((ext_vector_type(8)));
typedef float f32x4  __attribute__((ext_vector_type(4)));

__device__ __forceinline__ float lo2f(u32 p){ return __uint_as_float(p << 16); }
__device__ __forceinline__ float hi2f(u32 p){ return __uint_as_float(p & 0xFFFF0000u); }
__device__ __forceinline__ u16 f2bf(float f){
    u32 u = __float_as_uint(f);
    return (u16)((u + 0x7fffu + ((u >> 16) & 1u)) >> 16);   // RNE
}

// ---------------- CSR build ----------------
__global__ void k_hist(const int* __restrict__ dst, int* __restrict__ deg, int E){
    int i = blockIdx.x*256 + threadIdx.x;
    if (i < E) atomicAdd(&deg[dst[i]], 1);
}

__global__ void k_chunksum(const int* __restrict__ deg, int* __restrict__ csum,
                           float* __restrict__ invdeg, int n){
    __shared__ int sdata[256];
    int t = threadIdx.x;
    int i0 = blockIdx.x*512 + t*2;
    int a = (i0     < n) ? deg[i0]   : 0;
    int b = (i0 + 1 < n) ? deg[i0+1] : 0;
    if (i0     < n) invdeg[i0]   = 1.0f / (float)max(a, 1);
    if (i0 + 1 < n) invdeg[i0+1] = 1.0f / (float)max(b, 1);
    sdata[t] = a + b; __syncthreads();
    for (int off = 128; off > 0; off >>= 1){
        if (t < off) sdata[t] += sdata[t+off];
        __syncthreads();
    }
    if (t == 0) csum[blockIdx.x] = sdata[0];
}

__global__ void k_scanchunks(int* __restrict__ csum, int nchunks,
                             int* __restrict__ row_ptr, int n){
    __shared__ int s[256];
    __shared__ int carry_sh;
    int t = threadIdx.x;
    if (t == 0) carry_sh = 0;
    __syncthreads();
    for (int base = 0; base < nchunks; base += 256){
        int i = base + t;
        int v = (i < nchunks) ? csum[i] : 0;
        s[t] = v;
        __syncthreads();
        for (int off = 1; off < 256; off <<= 1){
            int u = (t >= off) ? s[t-off] : 0;
            __syncthreads();
            s[t] += u;
            __syncthreads();
        }
        int carry = carry_sh;
        int excl  = carry + s[t] - v;
        if (i < nchunks) csum[i] = excl;
        int tot = s[255];
        __syncthreads();
        if (t == 0) carry_sh = carry + tot;
        __syncthreads();
    }
    if (t == 0) row_ptr[n] = carry_sh;
}

__global__ void k_scanwithin(const int* __restrict__ deg, const int* __restrict__ csum,
                             int* __restrict__ row_ptr, int* __restrict__ cursor, int n){
    __shared__ int s[256];
    int t = threadIdx.x;
    int i0 = blockIdx.x*512 + t*2;
    int a = (i0     < n) ? deg[i0]   : 0;
    int b = (i0 + 1 < n) ? deg[i0+1] : 0;
    int tsum = a + b;
    s[t] = tsum; __syncthreads();
    for (int off = 1; off < 256; off <<= 1){
        int v = (t >= off) ? s[t-off] : 0;
        __syncthreads();
        s[t] += v;
        __syncthreads();
    }
    int excl = s[t] - tsum + csum[blockIdx.x];
    if (i0     < n){ row_ptr[i0]   = excl;     cursor[i0]   = excl;     }
    if (i0 + 1 < n){ row_ptr[i0+1] = excl + a; cursor[i0+1] = excl + a; }
}

__global__ void k_fill(const int* __restrict__ src, const int* __restrict__ dst,
                       int* __restrict__ cursor, int* __restrict__ sorted_src, int E){
    int i = blockIdx.x*256 + threadIdx.x;
    if (i < E){
        int p = atomicAdd(&cursor[dst[i]], 1);
        sorted_src[p] = src[i];
    }
}

__global__ void k_w2b3(const float* __restrict__ w0, const float* __restrict__ w1,
                       const float* __restrict__ w2,
                       u16* __restrict__ o0, u16* __restrict__ o1, u16* __restrict__ o2,
                       int nw){
    int i = blockIdx.x*256 + threadIdx.x;
    if (i >= nw) return;
    const float* s = (blockIdx.y == 0) ? w0 : (blockIdx.y == 1) ? w1 : w2;
    u16*         o = (blockIdx.y == 0) ? o0 : (blockIdx.y == 1) ? o1 : o2;
    o[i] = f2bf(s[i]);
}

// ---------------- MFMA GEMM + fused pre/post transforms ----------------
// PRE : 0 none | 1 logmap0 row-scale | 2 l2norm row-scale
// POST: 0 none | 1 l2norm ; RS = output row stride in u16
template<int PRE, int POST>
__device__ __forceinline__ void gemm_body(const float* __restrict__ X, const u16* __restrict__ Wb,
                                          const float* __restrict__ bias, u16* __restrict__ Y,
                                          int RS, int n_rows, const float* __restrict__ cptr){
    int t = threadIdx.x;
    int wave = t >> 6, lane = t & 63;
    int q = lane >> 4, m = lane & 15;
    int rowbase = blockIdx.x*64 + wave*16;
    int gr = min(rowbase + m, n_rows - 1);

    float4 xv[8];
    const float4* xp = (const float4*)(X + (size_t)gr*DD);
    #pragma unroll
    for (int c = 0; c < 4; c++){
        xv[2*c]   = xp[c*8 + q*2];
        xv[2*c+1] = xp[c*8 + q*2 + 1];
    }

    float scale = 1.0f;
    if (PRE != 0){
        float ss = 0.f;
        #pragma unroll
        for (int i = 0; i < 8; i++)
            ss += xv[i].x*xv[i].x + xv[i].y*xv[i].y + xv[i].z*xv[i].z + xv[i].w*xv[i].w;
        ss += __shfl_xor(ss, 16, 64);
        ss += __shfl_xor(ss, 32, 64);
        float nrm = sqrtf(ss);
        if (PRE == 1){
            float c  = cptr[0];
            c = (c > 0.f && c < 1e30f) ? c : 1.0f;
            float sc = sqrtf(c);
            float n2 = fmaxf(nrm, 1e-10f);
            float a  = fminf(sc*n2, 0.99999994f);
            scale = (2.0f/sc) * atanhf(a) / n2;
        } else {
            scale = 1.0f / fmaxf(nrm, 1e-12f);
        }
    }

    bf16x8 af[4];
    #pragma unroll
    for (int c = 0; c < 4; c++){
        const float* xf = (const float*)&xv[2*c];
        #pragma unroll
        for (int j = 0; j < 8; j++) af[c][j] = (short)f2bf(xf[j]*scale);
    }

    f32x4 acc[8];
    #pragma unroll
    for (int tl = 0; tl < 8; tl++) acc[tl] = (f32x4){0.f,0.f,0.f,0.f};

    const u16* wb = Wb + (size_t)m*DD + q*8;
    #pragma unroll
    for (int c = 0; c < 4; c++){
        #pragma unroll
        for (int tl = 0; tl < 8; tl++){
            bf16x8 bfr = *(const bf16x8*)(wb + (size_t)tl*16*DD + c*32);
            acc[tl] = __builtin_amdgcn_mfma_f32_16x16x32_bf16(af[c], bfr, acc[tl], 0, 0, 0);
        }
    }

    #pragma unroll
    for (int tl = 0; tl < 8; tl++){
        float bv = bias[tl*16 + m];
        #pragma unroll
        for (int r = 0; r < 4; r++) acc[tl][r] += bv;
    }
    if (POST == 1){
        float ssr[4] = {0.f,0.f,0.f,0.f};
        #pragma unroll
        for (int tl = 0; tl < 8; tl++)
            #pragma unroll
            for (int r = 0; r < 4; r++) ssr[r] += acc[tl][r]*acc[tl][r];
        #pragma unroll
        for (int r = 0; r < 4; r++){
            float s = ssr[r];
            s += __shfl_xor(s, 1, 64);
            s += __shfl_xor(s, 2, 64);
            s += __shfl_xor(s, 4, 64);
            s += __shfl_xor(s, 8, 64);
            float sc = 1.0f / fmaxf(sqrtf(s), 1e-12f);
            #pragma unroll
            for (int tl = 0; tl < 8; tl++) acc[tl][r] *= sc;
        }
    }
    #pragma unroll
    for (int r = 0; r < 4; r++){
        int grow = rowbase + q*4 + r;
        if (grow < n_rows){
            #pragma unroll
            for (int tl = 0; tl < 8; tl++)
                Y[(size_t)grow*RS + tl*16 + m] = f2bf(acc[tl][r]);
        }
    }
}

// PREB: layer0 = 1 (logmap0 on ball input), later layers = 0 (identity:
// log_map(0, exp_map(0, v)) == v). e -> hEB cols 0-127, b -> hEB cols 128-255,
// s -> hS (l2norm idempotent).
template<int PREB>
__global__ __launch_bounds__(256, 4)
void k_gemm3(const float* __restrict__ Xe, const float* __restrict__ Xb, const float* __restrict__ Xs,
             const u16* __restrict__ We, const u16* __restrict__ Wh, const u16* __restrict__ Ws,
             const float* __restrict__ be, const float* __restrict__ bb, const float* __restrict__ bs,
             u16* __restrict__ hEB, u16* __restrict__ hS,
             int n_rows, const float* __restrict__ cptr){
    if (blockIdx.y == 0)      gemm_body<0,0>(Xe, We, be, hEB,       256, n_rows, cptr);
    else if (blockIdx.y == 1) gemm_body<PREB,0>(Xb, Wh, bb, hEB+128, 256, n_rows, cptr);
    else                      gemm_body<2,1>(Xs, Ws, bs, hS,        128, n_rows, cptr);
}

// ---------------- XCD-sharded aggregation, group-per-node, shuffle-free ----
// blockIdx % 8 -> XCD (round-robin). Column-chunk x node-range tiling:
//  pass A: hEB (512B rows) = 4 chunks x 2 node-halves   -> 3.2MB/XCD (< 4MiB L2)
//  pass B: hS  (256B rows) = 2 chunks x 4 node-quarters -> 1.6MB/XCD
// Wave = 8 groups x 8 lanes; each GROUP owns one node, each LANE owns a fixed
// 16B column slice -> serial accumulate over edges, NO shuffles, direct store.
// NT stores (outputs) + NT loads (edge stream) keep the L2 for the gather table.
#define NPG 4              // nodes per group per block (block covers 32*NPG nodes)
__device__ __forceinline__ void acc8(float* a, uint4 p){
    a[0] += lo2f(p.x); a[1] += hi2f(p.x);
    a[2] += lo2f(p.y); a[3] += hi2f(p.y);
    a[4] += lo2f(p.z); a[5] += hi2f(p.z);
    a[6] += lo2f(p.w); a[7] += hi2f(p.w);
}

__global__ __launch_bounds__(256)
void k_aggT(const u32* __restrict__ hEB, const u32* __restrict__ hS,
            const int* __restrict__ row_ptr, const int* __restrict__ sorted_src,
            const float* __restrict__ invdeg,
            float* __restrict__ oE, float* __restrict__ oB, float* __restrict__ oS,
            int n_rows){
    const int NPB = 32*NPG;
    int xcd = blockIdx.x & 7;
    int idx = blockIdx.x >> 3;
    int nbA = (((n_rows + 1) >> 1) + NPB - 1) / NPB;
    int nbB = (((n_rows + 3) >> 2) + NPB - 1) / NPB;

    const u32* table; int rs, coff, nodebase, hi, outcol0, path;
    if (idx < nbA){
        int hf  = xcd & 1;
        int loA = (int)(((long long)n_rows * hf) >> 1);
        int hiA = (int)(((long long)n_rows * (hf+1)) >> 1);
        int cA  = xcd >> 1;                   // 0..3 over eb row
        table = hEB; rs = 128; coff = cA*32;  // u32 units: 512B row, 128B chunk
        nodebase = loA + idx*NPB; hi = hiA;
        path = cA >> 1; outcol0 = (cA & 1)*64;
    } else {
        int i2 = idx - nbA;
        if (i2 >= nbB) return;
        int qd  = xcd & 3;
        int loB = (int)(((long long)n_rows * qd) >> 2);
        int hiB = (int)(((long long)n_rows * (qd+1)) >> 2);
        int cS  = xcd >> 2;                   // 0..1 over s row
        table = hS; rs = 64; coff = cS*32;
        nodebase = loB + i2*NPB; hi = hiB;
        path = 2; outcol0 = cS*64;
    }
    float* dest = (path == 0) ? oE : (path == 1) ? oB : oS;
    bool leaky = (path == 0);

    int grp = threadIdx.x >> 3;        // 0..31, one node per group
    int l8  = threadIdx.x & 7;         // fixed 16B column slice
    const u32* tbl = table + coff + l8*4;

    #pragma unroll
    for (int k = 0; k < NPG; k++){
        int v = nodebase + k*32 + grp; // consecutive groups -> consecutive nodes
        if (v >= hi) continue;
        int beg = row_ptr[v], end = row_ptr[v+1];
        float a[8];
        #pragma unroll
        for (int i = 0; i < 8; i++) a[i] = 0.f;

        int p = beg;
        for (; p + 1 < end; p += 2){            // 2-deep per group, 8 groups/wave
            int i0 = __builtin_nontemporal_load(sorted_src + p);
            int i1 = __builtin_nontemporal_load(sorted_src + p + 1);
            uint4 c0 = *(const uint4*)(tbl + (size_t)i0*rs);
            uint4 c1 = *(const uint4*)(tbl + (size_t)i1*rs);
            acc8(a, c0); acc8(a, c1);
        }
        if (p < end){
            int i0 = __builtin_nontemporal_load(sorted_src + p);
            uint4 c0 = *(const uint4*)(tbl + (size_t)i0*rs);
            acc8(a, c0);
        }

        float inv = invdeg[v];
        f32x4 o0, o1;
        #pragma unroll
        for (int i = 0; i < 4; i++){
            float x = a[i]*inv;
            o0[i] = (leaky && x < 0.f) ? 0.2f*x : x;
        }
        #pragma unroll
        for (int i = 0; i < 4; i++){
            float x = a[4+i]*inv;
            o1[i] = (leaky && x < 0.f) ? 0.2f*x : x;
        }
        f32x4* dp = (f32x4*)(dest + (size_t)v*DD + outcol0 + l8*8);
        __builtin_nontemporal_store(o0, dp);
        __builtin_nontemporal_store(o1, dp+1);
    }
}

// ---------------- final-layer b/s epilogues (expmap0 / l2norm) ----------------
__global__ __launch_bounds__(256)
void k_final(const float* __restrict__ tb, const float* __restrict__ ts,
             float* __restrict__ ob, float* __restrict__ os,
             int n_rows, const float* __restrict__ cptr){
    int wid = (blockIdx.x*256 + threadIdx.x) >> 6;
    if (wid >= n_rows) return;
    int lane = threadIdx.x & 63;
    float2 vb = *(const float2*)(tb + (size_t)wid*DD + lane*2);
    float2 vs = *(const float2*)(ts + (size_t)wid*DD + lane*2);
    float ssb = vb.x*vb.x + vb.y*vb.y;
    float sss = vs.x*vs.x + vs.y*vs.y;
    #pragma unroll
    for (int m = 32; m > 0; m >>= 1){
        ssb += __shfl_xor(ssb, m, 64);
        sss += __shfl_xor(sss, m, 64);
    }
    float cc = cptr[0];
    cc = (cc > 0.f && cc < 1e30f) ? cc : 1.0f;
    float sc = sqrtf(cc);
    float nb = fmaxf(sqrtf(ssb), 1e-10f);
    float scb = tanhf(sc*nb*0.5f) / (sc*nb);
    float scs = 1.0f / fmaxf(sqrtf(sss), 1e-12f);
    *(float2*)(ob + (size_t)wid*DD + lane*2) = make_float2(vb.x*scb, vb.y*scb);
    *(float2*)(os + (size_t)wid*DD + lane*2) = make_float2(vs.x*scs, vs.y*scs);
}

extern "C" void kernel_launch(void* const* d_in, const int* in_sizes, int n_in,
                              void* d_out, int out_size, void* d_ws, size_t ws_size,
                              hipStream_t stream){
    const int*   src = (const int*)d_in[0];
    const int*   dst = (const int*)d_in[1];
    const float* emb_in[3] = {(const float*)d_in[2], (const float*)d_in[3], (const float*)d_in[4]};
    const float* W_in[3]   = {(const float*)d_in[5], (const float*)d_in[7], (const float*)d_in[9]};
    const float* b_in[3]   = {(const float*)d_in[6], (const float*)d_in[8], (const float*)d_in[10]};
    const float* b_c       = (const float*)d_in[11];

    const int E  = in_sizes[0];
    const int ND = in_sizes[2];
    const int N  = ND / DD;
    const int Lnum = in_sizes[5] / (DD*DD);
    const int nw = Lnum*DD*DD;
    const int nchunks = (N + 511) / 512;

    char* w = (char*)d_ws;
    auto alloc = [&](size_t bytes)->char*{
        char* p = w; w += (bytes + 255) & ~(size_t)255; return p;
    };
    u32*   hEB       = (u32*)  alloc((size_t)ND*4);     // [N][256 u16] e|b packed
    u32*   hS        = (u32*)  alloc((size_t)ND*2);     // [N][128 u16] s
    float* tb        = (float*)alloc((size_t)ND*4);     // final-layer raw means
    float* ts        = (float*)alloc((size_t)ND*4);
    u16*   Wb[3];
    for (int i = 0; i < 3; i++) Wb[i] = (u16*)alloc((size_t)nw*2);
    float* invdeg    = (float*)alloc((size_t)N*4);
    int*   deg       = (int*)  alloc((size_t)N*4);
    int*   row_ptr   = (int*)  alloc((size_t)(N+1)*4);
    int*   cursor    = (int*)  alloc((size_t)N*4);
    int*   csum      = (int*)  alloc((size_t)nchunks*4);
    int*   sorted_src= (int*)  alloc((size_t)E*4);
    (void)ws_size; (void)n_in; (void)out_size;

    float* out_e = (float*)d_out;
    float* out_b = out_e + ND;
    float* out_s = out_e + 2*ND;

    hipMemsetAsync(deg, 0, (size_t)N*4, stream);

    const int TB = 256;
    k_w2b3<<<dim3((nw+TB-1)/TB, 3), TB, 0, stream>>>(W_in[0], W_in[1], W_in[2],
                                                     Wb[0], Wb[1], Wb[2], nw);
    k_hist<<<(E+TB-1)/TB, TB, 0, stream>>>(dst, deg, E);
    k_chunksum<<<nchunks, 256, 0, stream>>>(deg, csum, invdeg, N);
    k_scanchunks<<<1, 256, 0, stream>>>(csum, nchunks, row_ptr, N);
    k_scanwithin<<<nchunks, 256, 0, stream>>>(deg, csum, row_ptr, cursor, N);
    k_fill<<<(E+TB-1)/TB, TB, 0, stream>>>(src, dst, cursor, sorted_src, E);

    const int gemmblocks = (N + 63) / 64;
    const int NPB = 32*NPG;
    const int nbA = (((N+1)/2) + NPB-1) / NPB;
    const int nbB = (((N+3)/4) + NPB-1) / NPB;
    const int aggblocks = 8 * (nbA + nbB);
    const int finblocks = (N + 3) / 4;

    const float* se = emb_in[0];
    const float* sb = emb_in[1];
    const float* ss = emb_in[2];

    for (int l = 0; l < Lnum; l++){
        bool last = (l == Lnum - 1);
        if (l == 0)
            k_gemm3<1><<<dim3(gemmblocks, 3), 256, 0, stream>>>(
                se, sb, ss,
                Wb[0] + (size_t)l*DD*DD, Wb[1] + (size_t)l*DD*DD, Wb[2] + (size_t)l*DD*DD,
                b_in[0] + (size_t)l*DD,  b_in[1] + (size_t)l*DD,  b_in[2] + (size_t)l*DD,
                (u16*)hEB, (u16*)hS, N, b_c);
        else
            k_gemm3<0><<<dim3(gemmblocks, 3), 256, 0, stream>>>(
                se, sb, ss,
                Wb[0] + (size_t)l*DD*DD, Wb[1] + (size_t)l*DD*DD, Wb[2] + (size_t)l*DD*DD,
                b_in[0] + (size_t)l*DD,  b_in[1] + (size_t)l*DD,  b_in[2] + (size_t)l*DD,
                (u16*)hEB, (u16*)hS, N, b_c);

        float* dB = last ? tb : out_b;
        float* dS = last ? ts : out_s;
        k_aggT<<<aggblocks, 256, 0, stream>>>(hEB, hS, row_ptr, sorted_src, invdeg,
                                              out_e, dB, dS, N);
        if (last)
            k_final<<<finblocks, 256, 0, stream>>>(tb, ts, out_b, out_s, N, b_c);

        se = out_e; sb = out_b; ss = out_s;
    }
}

// Round 5
// 542.080 us; speedup vs baseline: 1.1732x; 1.1732x over previous
//
#include <hip/hip_runtime.h>
#include <math.h>

#define DD 128
typedef unsigned int   u32;
typedef unsigned short u16;
typedef short bf16x8 __attribute__((ext_vector_type(8)));
typedef float f32x4  __attribute__((ext_vector_type(4)));

__device__ __forceinline__ float lo2f(u32 p){ return __uint_as_float(p << 16); }
__device__ __forceinline__ float hi2f(u32 p){ return __uint_as_float(p & 0xFFFF0000u); }
__device__ __forceinline__ u16 f2bf(float f){
    u32 u = __float_as_uint(f);
    return (u16)((u + 0x7fffu + ((u >> 16) & 1u)) >> 16);   // RNE
}

// ---------------- CSR build ----------------
__global__ void k_hist(const int* __restrict__ dst, int* __restrict__ deg, int E){
    int i = blockIdx.x*256 + threadIdx.x;
    if (i < E) atomicAdd(&deg[dst[i]], 1);
}

__global__ void k_chunksum(const int* __restrict__ deg, int* __restrict__ csum,
                           float* __restrict__ invdeg, int n){
    __shared__ int sdata[256];
    int t = threadIdx.x;
    int i0 = blockIdx.x*512 + t*2;
    int a = (i0     < n) ? deg[i0]   : 0;
    int b = (i0 + 1 < n) ? deg[i0+1] : 0;
    if (i0     < n) invdeg[i0]   = 1.0f / (float)max(a, 1);
    if (i0 + 1 < n) invdeg[i0+1] = 1.0f / (float)max(b, 1);
    sdata[t] = a + b; __syncthreads();
    for (int off = 128; off > 0; off >>= 1){
        if (t < off) sdata[t] += sdata[t+off];
        __syncthreads();
    }
    if (t == 0) csum[blockIdx.x] = sdata[0];
}

__global__ void k_scanchunks(int* __restrict__ csum, int nchunks,
                             int* __restrict__ row_ptr, int n){
    __shared__ int s[256];
    __shared__ int carry_sh;
    int t = threadIdx.x;
    if (t == 0) carry_sh = 0;
    __syncthreads();
    for (int base = 0; base < nchunks; base += 256){
        int i = base + t;
        int v = (i < nchunks) ? csum[i] : 0;
        s[t] = v;
        __syncthreads();
        for (int off = 1; off < 256; off <<= 1){
            int u = (t >= off) ? s[t-off] : 0;
            __syncthreads();
            s[t] += u;
            __syncthreads();
        }
        int carry = carry_sh;
        int excl  = carry + s[t] - v;
        if (i < nchunks) csum[i] = excl;
        int tot = s[255];
        __syncthreads();
        if (t == 0) carry_sh = carry + tot;
        __syncthreads();
    }
    if (t == 0) row_ptr[n] = carry_sh;
}

__global__ void k_scanwithin(const int* __restrict__ deg, const int* __restrict__ csum,
                             int* __restrict__ row_ptr, int* __restrict__ cursor, int n){
    __shared__ int s[256];
    int t = threadIdx.x;
    int i0 = blockIdx.x*512 + t*2;
    int a = (i0     < n) ? deg[i0]   : 0;
    int b = (i0 + 1 < n) ? deg[i0+1] : 0;
    int tsum = a + b;
    s[t] = tsum; __syncthreads();
    for (int off = 1; off < 256; off <<= 1){
        int v = (t >= off) ? s[t-off] : 0;
        __syncthreads();
        s[t] += v;
        __syncthreads();
    }
    int excl = s[t] - tsum + csum[blockIdx.x];
    if (i0     < n){ row_ptr[i0]   = excl;     cursor[i0]   = excl;     }
    if (i0 + 1 < n){ row_ptr[i0+1] = excl + a; cursor[i0+1] = excl + a; }
}

__global__ void k_fill(const int* __restrict__ src, const int* __restrict__ dst,
                       int* __restrict__ cursor, int* __restrict__ sorted_src, int E){
    int i = blockIdx.x*256 + threadIdx.x;
    if (i < E){
        int p = atomicAdd(&cursor[dst[i]], 1);
        sorted_src[p] = src[i];
    }
}

__global__ void k_w2b3(const float* __restrict__ w0, const float* __restrict__ w1,
                       const float* __restrict__ w2,
                       u16* __restrict__ o0, u16* __restrict__ o1, u16* __restrict__ o2,
                       int nw){
    int i = blockIdx.x*256 + threadIdx.x;
    if (i >= nw) return;
    const float* s = (blockIdx.y == 0) ? w0 : (blockIdx.y == 1) ? w1 : w2;
    u16*         o = (blockIdx.y == 0) ? o0 : (blockIdx.y == 1) ? o1 : o2;
    o[i] = f2bf(s[i]);
}

// ---------------- MFMA GEMM + fused pre/post transforms ----------------
// PRE : 0 none | 1 logmap0 row-scale | 2 l2norm row-scale
// POST: 0 none | 1 l2norm
// Output goes to SHARD-MAJOR layout: Y = shard base; col (tl*16+m) lands in
// shard (col>>5) at [row*32 + (col&31)]; shard stride = sstride u16.
template<int PRE, int POST>
__device__ __forceinline__ void gemm_body(const float* __restrict__ X, const u16* __restrict__ Wb,
                                          const float* __restrict__ bias, u16* __restrict__ Y,
                                          size_t sstride, int n_rows, const float* __restrict__ cptr){
    int t = threadIdx.x;
    int wave = t >> 6, lane = t & 63;
    int q = lane >> 4, m = lane & 15;
    int rowbase = blockIdx.x*64 + wave*16;
    int gr = min(rowbase + m, n_rows - 1);

    float4 xv[8];
    const float4* xp = (const float4*)(X + (size_t)gr*DD);
    #pragma unroll
    for (int c = 0; c < 4; c++){
        xv[2*c]   = xp[c*8 + q*2];
        xv[2*c+1] = xp[c*8 + q*2 + 1];
    }

    float scale = 1.0f;
    if (PRE != 0){
        float ss = 0.f;
        #pragma unroll
        for (int i = 0; i < 8; i++)
            ss += xv[i].x*xv[i].x + xv[i].y*xv[i].y + xv[i].z*xv[i].z + xv[i].w*xv[i].w;
        ss += __shfl_xor(ss, 16, 64);
        ss += __shfl_xor(ss, 32, 64);
        float nrm = sqrtf(ss);
        if (PRE == 1){
            float c  = cptr[0];
            c = (c > 0.f && c < 1e30f) ? c : 1.0f;
            float sc = sqrtf(c);
            float n2 = fmaxf(nrm, 1e-10f);
            float a  = fminf(sc*n2, 0.99999994f);
            scale = (2.0f/sc) * atanhf(a) / n2;
        } else {
            scale = 1.0f / fmaxf(nrm, 1e-12f);
        }
    }

    bf16x8 af[4];
    #pragma unroll
    for (int c = 0; c < 4; c++){
        const float* xf = (const float*)&xv[2*c];
        #pragma unroll
        for (int j = 0; j < 8; j++) af[c][j] = (short)f2bf(xf[j]*scale);
    }

    f32x4 acc[8];
    #pragma unroll
    for (int tl = 0; tl < 8; tl++) acc[tl] = (f32x4){0.f,0.f,0.f,0.f};

    const u16* wb = Wb + (size_t)m*DD + q*8;
    #pragma unroll
    for (int c = 0; c < 4; c++){
        #pragma unroll
        for (int tl = 0; tl < 8; tl++){
            bf16x8 bfr = *(const bf16x8*)(wb + (size_t)tl*16*DD + c*32);
            acc[tl] = __builtin_amdgcn_mfma_f32_16x16x32_bf16(af[c], bfr, acc[tl], 0, 0, 0);
        }
    }

    #pragma unroll
    for (int tl = 0; tl < 8; tl++){
        float bv = bias[tl*16 + m];
        #pragma unroll
        for (int r = 0; r < 4; r++) acc[tl][r] += bv;
    }
    if (POST == 1){
        float ssr[4] = {0.f,0.f,0.f,0.f};
        #pragma unroll
        for (int tl = 0; tl < 8; tl++)
            #pragma unroll
            for (int r = 0; r < 4; r++) ssr[r] += acc[tl][r]*acc[tl][r];
        #pragma unroll
        for (int r = 0; r < 4; r++){
            float s = ssr[r];
            s += __shfl_xor(s, 1, 64);
            s += __shfl_xor(s, 2, 64);
            s += __shfl_xor(s, 4, 64);
            s += __shfl_xor(s, 8, 64);
            float sc = 1.0f / fmaxf(sqrtf(s), 1e-12f);
            #pragma unroll
            for (int tl = 0; tl < 8; tl++) acc[tl][r] *= sc;
        }
    }
    #pragma unroll
    for (int r = 0; r < 4; r++){
        int grow = rowbase + q*4 + r;
        if (grow < n_rows){
            #pragma unroll
            for (int tl = 0; tl < 8; tl++)
                Y[(size_t)(tl>>1)*sstride + (size_t)grow*32 + (tl&1)*16 + m] = f2bf(acc[tl][r]);
        }
    }
}

// PREB: layer0 = 1 (logmap0 on ball input), later layers = 0 (identity:
// log_map(0, exp_map(0, v)) == v). e -> ebS shards 0-3, b -> ebS shards 4-7,
// s -> sS shards 0-3 (l2norm idempotent).
template<int PREB>
__global__ __launch_bounds__(256, 4)
void k_gemm3(const float* __restrict__ Xe, const float* __restrict__ Xb, const float* __restrict__ Xs,
             const u16* __restrict__ We, const u16* __restrict__ Wh, const u16* __restrict__ Ws,
             const float* __restrict__ be, const float* __restrict__ bb, const float* __restrict__ bs,
             u16* __restrict__ ebS, u16* __restrict__ sS,
             int n_rows, const float* __restrict__ cptr){
    size_t sstride = (size_t)n_rows * 32;
    if (blockIdx.y == 0)      gemm_body<0,0>(Xe, We, be, ebS,            sstride, n_rows, cptr);
    else if (blockIdx.y == 1) gemm_body<PREB,0>(Xb, Wh, bb, ebS+4*sstride, sstride, n_rows, cptr);
    else                      gemm_body<2,1>(Xs, Ws, bs, sS,             sstride, n_rows, cptr);
}

// ---------------- XCD-sharded aggregation, shard-contiguous tables --------
// Tables are shard-major: 12 shards of [N][64B] (ebS: 8 = e|b, sS: 4 = s).
// Per-XCD working set = 64B * N = 3.2MB < 4MiB L2, contiguous (no false share).
// blockIdx%8 -> XCD. eb jobs: shard = xcd, all nodes. s jobs: shard = xcd&3,
// node-half = xcd>>2 (8 balanced jobs).
// Wave = 16 groups x 4 lanes: group owns a node, lane owns 16B of the chunk.
// Serial accumulate over edges (no shuffles); regular cached index loads;
// NT stores only (128B contiguous per group).
#define NPG 2              // nodes per group per block (block covers 64*NPG)
__device__ __forceinline__ void acc8(float* a, uint4 p){
    a[0] += lo2f(p.x); a[1] += hi2f(p.x);
    a[2] += lo2f(p.y); a[3] += hi2f(p.y);
    a[4] += lo2f(p.z); a[5] += hi2f(p.z);
    a[6] += lo2f(p.w); a[7] += hi2f(p.w);
}

__global__ __launch_bounds__(256)
void k_aggT(const u32* __restrict__ ebS, const u32* __restrict__ sS,
            const int* __restrict__ row_ptr, const int* __restrict__ sorted_src,
            const float* __restrict__ invdeg,
            float* __restrict__ oE, float* __restrict__ oB, float* __restrict__ oS,
            int n_rows){
    const int NPB = 64*NPG;
    int xcd = blockIdx.x & 7;
    int idx = blockIdx.x >> 3;
    int nbE = (n_rows + NPB - 1) / NPB;
    size_t sstride = (size_t)n_rows * 16;      // u32 per shard

    const u32* shard; float* dest; int nodebase, hi, colbase; bool leaky;
    if (idx < nbE){
        int c = xcd;                           // eb shard 0..7
        shard = ebS + (size_t)c * sstride;
        dest = (c < 4) ? oE : oB;
        leaky = (c < 4);
        colbase = (c & 3) * 32;
        nodebase = idx * NPB; hi = n_rows;
    } else {
        int half = xcd >> 2, c = xcd & 3;      // s shard 0..3, node half
        int lo  = (int)(((long long)n_rows * half) >> 1);
        int hi2 = (int)(((long long)n_rows * (half+1)) >> 1);
        int nbS = (hi2 - lo + NPB - 1) / NPB;
        int i2 = idx - nbE;
        if (i2 >= nbS) return;
        shard = sS + (size_t)c * sstride;
        dest = oS; leaky = false;
        colbase = c * 32;
        nodebase = lo + i2*NPB; hi = hi2;
    }

    int grp = threadIdx.x >> 2;                // 0..63, one node per group
    int l4  = threadIdx.x & 3;                 // 16B column slice
    const u32* tbl = shard + l4*4;

    #pragma unroll
    for (int k = 0; k < NPG; k++){
        int v = nodebase + k*64 + grp;         // consecutive groups -> consec nodes
        if (v >= hi) continue;
        int beg = row_ptr[v], end = row_ptr[v+1];
        float a[8];
        #pragma unroll
        for (int i = 0; i < 8; i++) a[i] = 0.f;

        int p = beg;
        for (; p + 1 < end; p += 2){           // 2-deep, 16 groups/wave in flight
            int i0 = sorted_src[p];
            int i1 = sorted_src[p+1];
            uint4 c0 = *(const uint4*)(tbl + (size_t)i0*16);
            uint4 c1 = *(const uint4*)(tbl + (size_t)i1*16);
            acc8(a, c0); acc8(a, c1);
        }
        if (p < end){
            int i0 = sorted_src[p];
            uint4 c0 = *(const uint4*)(tbl + (size_t)i0*16);
            acc8(a, c0);
        }

        float inv = invdeg[v];
        f32x4 o0, o1;
        #pragma unroll
        for (int i = 0; i < 4; i++){
            float x = a[i]*inv;
            o0[i] = (leaky && x < 0.f) ? 0.2f*x : x;
        }
        #pragma unroll
        for (int i = 0; i < 4; i++){
            float x = a[4+i]*inv;
            o1[i] = (leaky && x < 0.f) ? 0.2f*x : x;
        }
        f32x4* dp = (f32x4*)(dest + (size_t)v*DD + colbase + l4*8);
        __builtin_nontemporal_store(o0, dp);
        __builtin_nontemporal_store(o1, dp+1);
    }
}

// ---------------- final-layer b/s epilogues (expmap0 / l2norm) ----------------
__global__ __launch_bounds__(256)
void k_final(const float* __restrict__ tb, const float* __restrict__ ts,
             float* __restrict__ ob, float* __restrict__ os,
             int n_rows, const float* __restrict__ cptr){
    int wid = (blockIdx.x*256 + threadIdx.x) >> 6;
    if (wid >= n_rows) return;
    int lane = threadIdx.x & 63;
    float2 vb = *(const float2*)(tb + (size_t)wid*DD + lane*2);
    float2 vs = *(const float2*)(ts + (size_t)wid*DD + lane*2);
    float ssb = vb.x*vb.x + vb.y*vb.y;
    float sss = vs.x*vs.x + vs.y*vs.y;
    #pragma unroll
    for (int m = 32; m > 0; m >>= 1){
        ssb += __shfl_xor(ssb, m, 64);
        sss += __shfl_xor(sss, m, 64);
    }
    float cc = cptr[0];
    cc = (cc > 0.f && cc < 1e30f) ? cc : 1.0f;
    float sc = sqrtf(cc);
    float nb = fmaxf(sqrtf(ssb), 1e-10f);
    float scb = tanhf(sc*nb*0.5f) / (sc*nb);
    float scs = 1.0f / fmaxf(sqrtf(sss), 1e-12f);
    *(float2*)(ob + (size_t)wid*DD + lane*2) = make_float2(vb.x*scb, vb.y*scb);
    *(float2*)(os + (size_t)wid*DD + lane*2) = make_float2(vs.x*scs, vs.y*scs);
}

extern "C" void kernel_launch(void* const* d_in, const int* in_sizes, int n_in,
                              void* d_out, int out_size, void* d_ws, size_t ws_size,
                              hipStream_t stream){
    const int*   src = (const int*)d_in[0];
    const int*   dst = (const int*)d_in[1];
    const float* emb_in[3] = {(const float*)d_in[2], (const float*)d_in[3], (const float*)d_in[4]};
    const float* W_in[3]   = {(const float*)d_in[5], (const float*)d_in[7], (const float*)d_in[9]};
    const float* b_in[3]   = {(const float*)d_in[6], (const float*)d_in[8], (const float*)d_in[10]};
    const float* b_c       = (const float*)d_in[11];

    const int E  = in_sizes[0];
    const int ND = in_sizes[2];
    const int N  = ND / DD;
    const int Lnum = in_sizes[5] / (DD*DD);
    const int nw = Lnum*DD*DD;
    const int nchunks = (N + 511) / 512;

    char* w = (char*)d_ws;
    auto alloc = [&](size_t bytes)->char*{
        char* p = w; w += (bytes + 255) & ~(size_t)255; return p;
    };
    u32*   ebS       = (u32*)  alloc((size_t)ND*4);     // 8 shards [N][64B] (e|b)
    u32*   sS        = (u32*)  alloc((size_t)ND*2);     // 4 shards [N][64B] (s)
    float* tb        = (float*)alloc((size_t)ND*4);     // final-layer raw means
    float* ts        = (float*)alloc((size_t)ND*4);
    u16*   Wb[3];
    for (int i = 0; i < 3; i++) Wb[i] = (u16*)alloc((size_t)nw*2);
    float* invdeg    = (float*)alloc((size_t)N*4);
    int*   deg       = (int*)  alloc((size_t)N*4);
    int*   row_ptr   = (int*)  alloc((size_t)(N+1)*4);
    int*   cursor    = (int*)  alloc((size_t)N*4);
    int*   csum      = (int*)  alloc((size_t)nchunks*4);
    int*   sorted_src= (int*)  alloc((size_t)E*4);
    (void)ws_size; (void)n_in; (void)out_size;

    float* out_e = (float*)d_out;
    float* out_b = out_e + ND;
    float* out_s = out_e + 2*ND;

    hipMemsetAsync(deg, 0, (size_t)N*4, stream);

    const int TB = 256;
    k_w2b3<<<dim3((nw+TB-1)/TB, 3), TB, 0, stream>>>(W_in[0], W_in[1], W_in[2],
                                                     Wb[0], Wb[1], Wb[2], nw);
    k_hist<<<(E+TB-1)/TB, TB, 0, stream>>>(dst, deg, E);
    k_chunksum<<<nchunks, 256, 0, stream>>>(deg, csum, invdeg, N);
    k_scanchunks<<<1, 256, 0, stream>>>(csum, nchunks, row_ptr, N);
    k_scanwithin<<<nchunks, 256, 0, stream>>>(deg, csum, row_ptr, cursor, N);
    k_fill<<<(E+TB-1)/TB, TB, 0, stream>>>(src, dst, cursor, sorted_src, E);

    const int gemmblocks = (N + 63) / 64;
    const int NPB = 64*NPG;
    const int nbE = (N + NPB - 1) / NPB;
    const int nbS = (((N + 1) / 2) + NPB - 1) / NPB;
    const int aggblocks = 8 * (nbE + nbS);
    const int finblocks = (N + 3) / 4;

    const float* se = emb_in[0];
    const float* sb = emb_in[1];
    const float* ss = emb_in[2];

    for (int l = 0; l < Lnum; l++){
        bool last = (l == Lnum - 1);
        if (l == 0)
            k_gemm3<1><<<dim3(gemmblocks, 3), 256, 0, stream>>>(
                se, sb, ss,
                Wb[0] + (size_t)l*DD*DD, Wb[1] + (size_t)l*DD*DD, Wb[2] + (size_t)l*DD*DD,
                b_in[0] + (size_t)l*DD,  b_in[1] + (size_t)l*DD,  b_in[2] + (size_t)l*DD,
                (u16*)ebS, (u16*)sS, N, b_c);
        else
            k_gemm3<0><<<dim3(gemmblocks, 3), 256, 0, stream>>>(
                se, sb, ss,
                Wb[0] + (size_t)l*DD*DD, Wb[1] + (size_t)l*DD*DD, Wb[2] + (size_t)l*DD*DD,
                b_in[0] + (size_t)l*DD,  b_in[1] + (size_t)l*DD,  b_in[2] + (size_t)l*DD,
                (u16*)ebS, (u16*)sS, N, b_c);

        float* dB = last ? tb : out_b;
        float* dS = last ? ts : out_s;
        k_aggT<<<aggblocks, 256, 0, stream>>>(ebS, sS, row_ptr, sorted_src, invdeg,
                                              out_e, dB, dS, N);
        if (last)
            k_final<<<finblocks, 256, 0, stream>>>(tb, ts, out_b, out_s, N, b_c);

        se = out_e; sb = out_b; ss = out_s;
    }
}

// Round 6
// 495.700 us; speedup vs baseline: 1.2830x; 1.0936x over previous
//
#include <hip/hip_runtime.h>
#include <math.h>

#define DD 128
typedef unsigned int   u32;
typedef unsigned short u16;
typedef short bf16x8 __attribute__((ext_vector_type(8)));
typedef float f32x4  __attribute__((ext_vector_type(4)));

__device__ __forceinline__ float lo2f(u32 p){ return __uint_as_float(p << 16); }
__device__ __forceinline__ float hi2f(u32 p){ return __uint_as_float(p & 0xFFFF0000u); }
__device__ __forceinline__ u16 f2bf(float f){
    u32 u = __float_as_uint(f);
    return (u16)((u + 0x7fffu + ((u >> 16) & 1u)) >> 16);   // RNE
}

// ---------------- CSR build ----------------
__global__ void k_hist(const int* __restrict__ dst, int* __restrict__ deg, int E){
    int i = blockIdx.x*256 + threadIdx.x;
    if (i < E) atomicAdd(&deg[dst[i]], 1);
}

__global__ void k_chunksum(const int* __restrict__ deg, int* __restrict__ csum,
                           float* __restrict__ invdeg, int n){
    __shared__ int sdata[256];
    int t = threadIdx.x;
    int i0 = blockIdx.x*512 + t*2;
    int a = (i0     < n) ? deg[i0]   : 0;
    int b = (i0 + 1 < n) ? deg[i0+1] : 0;
    if (i0     < n) invdeg[i0]   = 1.0f / (float)max(a, 1);
    if (i0 + 1 < n) invdeg[i0+1] = 1.0f / (float)max(b, 1);
    sdata[t] = a + b; __syncthreads();
    for (int off = 128; off > 0; off >>= 1){
        if (t < off) sdata[t] += sdata[t+off];
        __syncthreads();
    }
    if (t == 0) csum[blockIdx.x] = sdata[0];
}

__global__ void k_scanchunks(int* __restrict__ csum, int nchunks,
                             int* __restrict__ row_ptr, int n){
    __shared__ int s[256];
    __shared__ int carry_sh;
    int t = threadIdx.x;
    if (t == 0) carry_sh = 0;
    __syncthreads();
    for (int base = 0; base < nchunks; base += 256){
        int i = base + t;
        int v = (i < nchunks) ? csum[i] : 0;
        s[t] = v;
        __syncthreads();
        for (int off = 1; off < 256; off <<= 1){
            int u = (t >= off) ? s[t-off] : 0;
            __syncthreads();
            s[t] += u;
            __syncthreads();
        }
        int carry = carry_sh;
        int excl  = carry + s[t] - v;
        if (i < nchunks) csum[i] = excl;
        int tot = s[255];
        __syncthreads();
        if (t == 0) carry_sh = carry + tot;
        __syncthreads();
    }
    if (t == 0) row_ptr[n] = carry_sh;
}

__global__ void k_scanwithin(const int* __restrict__ deg, const int* __restrict__ csum,
                             int* __restrict__ row_ptr, int* __restrict__ cursor, int n){
    __shared__ int s[256];
    int t = threadIdx.x;
    int i0 = blockIdx.x*512 + t*2;
    int a = (i0     < n) ? deg[i0]   : 0;
    int b = (i0 + 1 < n) ? deg[i0+1] : 0;
    int tsum = a + b;
    s[t] = tsum; __syncthreads();
    for (int off = 1; off < 256; off <<= 1){
        int v = (t >= off) ? s[t-off] : 0;
        __syncthreads();
        s[t] += v;
        __syncthreads();
    }
    int excl = s[t] - tsum + csum[blockIdx.x];
    if (i0     < n){ row_ptr[i0]   = excl;     cursor[i0]   = excl;     }
    if (i0 + 1 < n){ row_ptr[i0+1] = excl + a; cursor[i0+1] = excl + a; }
}

// IT = u16 when N <= 65535 (halves index fetch + stream pollution), else int.
template<typename IT>
__global__ void k_fill(const int* __restrict__ src, const int* __restrict__ dst,
                       int* __restrict__ cursor, IT* __restrict__ sorted_src, int E){
    int i = blockIdx.x*256 + threadIdx.x;
    if (i < E){
        int p = atomicAdd(&cursor[dst[i]], 1);
        sorted_src[p] = (IT)src[i];
    }
}

__global__ void k_w2b3(const float* __restrict__ w0, const float* __restrict__ w1,
                       const float* __restrict__ w2,
                       u16* __restrict__ o0, u16* __restrict__ o1, u16* __restrict__ o2,
                       int nw){
    int i = blockIdx.x*256 + threadIdx.x;
    if (i >= nw) return;
    const float* s = (blockIdx.y == 0) ? w0 : (blockIdx.y == 1) ? w1 : w2;
    u16*         o = (blockIdx.y == 0) ? o0 : (blockIdx.y == 1) ? o1 : o2;
    o[i] = f2bf(s[i]);
}

// ---------------- MFMA GEMM + fused pre/post transforms ----------------
// PRE : 0 none | 1 logmap0 row-scale | 2 l2norm row-scale
// POST: 0 none | 1 l2norm
// Output SHARD-MAJOR: col (tl*16+m) -> shard (col>>5) at [row*32 + (col&31)].
template<int PRE, int POST>
__device__ __forceinline__ void gemm_body(const float* __restrict__ X, const u16* __restrict__ Wb,
                                          const float* __restrict__ bias, u16* __restrict__ Y,
                                          size_t sstride, int n_rows, const float* __restrict__ cptr){
    int t = threadIdx.x;
    int wave = t >> 6, lane = t & 63;
    int q = lane >> 4, m = lane & 15;
    int rowbase = blockIdx.x*64 + wave*16;
    int gr = min(rowbase + m, n_rows - 1);

    float4 xv[8];
    const float4* xp = (const float4*)(X + (size_t)gr*DD);
    #pragma unroll
    for (int c = 0; c < 4; c++){
        xv[2*c]   = xp[c*8 + q*2];
        xv[2*c+1] = xp[c*8 + q*2 + 1];
    }

    float scale = 1.0f;
    if (PRE != 0){
        float ss = 0.f;
        #pragma unroll
        for (int i = 0; i < 8; i++)
            ss += xv[i].x*xv[i].x + xv[i].y*xv[i].y + xv[i].z*xv[i].z + xv[i].w*xv[i].w;
        ss += __shfl_xor(ss, 16, 64);
        ss += __shfl_xor(ss, 32, 64);
        float nrm = sqrtf(ss);
        if (PRE == 1){
            float c  = cptr[0];
            c = (c > 0.f && c < 1e30f) ? c : 1.0f;
            float sc = sqrtf(c);
            float n2 = fmaxf(nrm, 1e-10f);
            float a  = fminf(sc*n2, 0.99999994f);
            scale = (2.0f/sc) * atanhf(a) / n2;
        } else {
            scale = 1.0f / fmaxf(nrm, 1e-12f);
        }
    }

    bf16x8 af[4];
    #pragma unroll
    for (int c = 0; c < 4; c++){
        const float* xf = (const float*)&xv[2*c];
        #pragma unroll
        for (int j = 0; j < 8; j++) af[c][j] = (short)f2bf(xf[j]*scale);
    }

    f32x4 acc[8];
    #pragma unroll
    for (int tl = 0; tl < 8; tl++) acc[tl] = (f32x4){0.f,0.f,0.f,0.f};

    const u16* wb = Wb + (size_t)m*DD + q*8;
    #pragma unroll
    for (int c = 0; c < 4; c++){
        #pragma unroll
        for (int tl = 0; tl < 8; tl++){
            bf16x8 bfr = *(const bf16x8*)(wb + (size_t)tl*16*DD + c*32);
            acc[tl] = __builtin_amdgcn_mfma_f32_16x16x32_bf16(af[c], bfr, acc[tl], 0, 0, 0);
        }
    }

    #pragma unroll
    for (int tl = 0; tl < 8; tl++){
        float bv = bias[tl*16 + m];
        #pragma unroll
        for (int r = 0; r < 4; r++) acc[tl][r] += bv;
    }
    if (POST == 1){
        float ssr[4] = {0.f,0.f,0.f,0.f};
        #pragma unroll
        for (int tl = 0; tl < 8; tl++)
            #pragma unroll
            for (int r = 0; r < 4; r++) ssr[r] += acc[tl][r]*acc[tl][r];
        #pragma unroll
        for (int r = 0; r < 4; r++){
            float s = ssr[r];
            s += __shfl_xor(s, 1, 64);
            s += __shfl_xor(s, 2, 64);
            s += __shfl_xor(s, 4, 64);
            s += __shfl_xor(s, 8, 64);
            float sc = 1.0f / fmaxf(sqrtf(s), 1e-12f);
            #pragma unroll
            for (int tl = 0; tl < 8; tl++) acc[tl][r] *= sc;
        }
    }
    #pragma unroll
    for (int r = 0; r < 4; r++){
        int grow = rowbase + q*4 + r;
        if (grow < n_rows){
            #pragma unroll
            for (int tl = 0; tl < 8; tl++)
                Y[(size_t)(tl>>1)*sstride + (size_t)grow*32 + (tl&1)*16 + m] = f2bf(acc[tl][r]);
        }
    }
}

// PREB: layer0 = 1 (logmap0 on ball input), later layers = 0 (identity:
// log_map(0, exp_map(0, v)) == v). e -> ebS shards 0-3, b -> ebS shards 4-7,
// s -> sS shards 0-3 (l2norm idempotent).
template<int PREB>
__global__ __launch_bounds__(256, 4)
void k_gemm3(const float* __restrict__ Xe, const float* __restrict__ Xb, const float* __restrict__ Xs,
             const u16* __restrict__ We, const u16* __restrict__ Wh, const u16* __restrict__ Ws,
             const float* __restrict__ be, const float* __restrict__ bb, const float* __restrict__ bs,
             u16* __restrict__ ebS, u16* __restrict__ sS,
             int n_rows, const float* __restrict__ cptr){
    size_t sstride = (size_t)n_rows * 32;
    if (blockIdx.y == 0)      gemm_body<0,0>(Xe, We, be, ebS,            sstride, n_rows, cptr);
    else if (blockIdx.y == 1) gemm_body<PREB,0>(Xb, Wh, bb, ebS+4*sstride, sstride, n_rows, cptr);
    else                      gemm_body<2,1>(Xs, Ws, bs, sS,             sstride, n_rows, cptr);
}

// ---------------- XCD-sharded aggregation, shard-contiguous tables --------
// Shard-major tables: 12 shards of [N][64B]. Per-XCD resident set = ONE shard
// (3.2MB < 4MiB L2). MODE 0 (eb): shard = xcd over 8, all nodes. MODE 1 (s):
// shard = xcd&3, node-half = xcd>>2. Two SEQUENTIAL dispatches so eb and s
// shards never share an XCD's L2.
// Wave = 16 groups x 4 lanes: group owns a node, lane owns a 16B slice.
// Edge loop: 4-deep gathers + next-quad index prefetch rotation -> index
// latency hides under accumulate; ~1 gather latency per 4 edges steady-state.
#define NPG 2              // nodes per group per block (block covers 64*NPG)
__device__ __forceinline__ void acc8(float* a, uint4 p){
    a[0] += lo2f(p.x); a[1] += hi2f(p.x);
    a[2] += lo2f(p.y); a[3] += hi2f(p.y);
    a[4] += lo2f(p.z); a[5] += hi2f(p.z);
    a[6] += lo2f(p.w); a[7] += hi2f(p.w);
}

template<typename IT, int MODE>
__global__ __launch_bounds__(256)
void k_aggT(const u32* __restrict__ tab,
            const int* __restrict__ row_ptr, const IT* __restrict__ sorted_src,
            const float* __restrict__ invdeg,
            float* __restrict__ oE, float* __restrict__ oB, float* __restrict__ oS,
            int n_rows){
    const int NPB = 64*NPG;
    int xcd = blockIdx.x & 7;
    int idx = blockIdx.x >> 3;
    size_t sstride = (size_t)n_rows * 16;      // u32 per shard

    const u32* shard; float* dest; int nodebase, hi, colbase; bool leaky;
    if (MODE == 0){
        shard = tab + (size_t)xcd * sstride;   // eb shard 0..7
        dest = (xcd < 4) ? oE : oB;
        leaky = (xcd < 4);
        colbase = (xcd & 3) * 32;
        nodebase = idx * NPB; hi = n_rows;
        if (nodebase >= hi) return;
    } else {
        int half = xcd >> 2, c = xcd & 3;      // s shard 0..3, node half
        int lo  = (int)(((long long)n_rows * half) >> 1);
        int hi2 = (int)(((long long)n_rows * (half+1)) >> 1);
        shard = tab + (size_t)c * sstride;
        dest = oS; leaky = false;
        colbase = c * 32;
        nodebase = lo + idx*NPB; hi = hi2;
        if (nodebase >= hi) return;
    }

    int grp = threadIdx.x >> 2;                // 0..63, one node per group
    int l4  = threadIdx.x & 3;                 // 16B column slice
    const u32* tbl = shard + l4*4;

    #pragma unroll
    for (int k = 0; k < NPG; k++){
        int v = nodebase + k*64 + grp;         // consecutive groups -> consec nodes
        if (v >= hi) continue;
        int beg = row_ptr[v], end = row_ptr[v+1];
        int cnt = end - beg;
        float a[8];
        #pragma unroll
        for (int i = 0; i < 8; i++) a[i] = 0.f;

        int nq = cnt >> 2;
        int p = beg;
        int j0 = 0, j1 = 0, j2 = 0, j3 = 0;
        if (nq > 0){
            j0 = (int)sorted_src[p]; j1 = (int)sorted_src[p+1];
            j2 = (int)sorted_src[p+2]; j3 = (int)sorted_src[p+3];
        }
        for (int q = 0; q < nq; q++){
            uint4 c0 = *(const uint4*)(tbl + (size_t)j0*16);
            uint4 c1 = *(const uint4*)(tbl + (size_t)j1*16);
            uint4 c2 = *(const uint4*)(tbl + (size_t)j2*16);
            uint4 c3 = *(const uint4*)(tbl + (size_t)j3*16);
            p += 4;
            if (q + 1 < nq){                   // prefetch next quad's indices:
                j0 = (int)sorted_src[p];       // issued before c0..c3 are consumed,
                j1 = (int)sorted_src[p+1];     // so idx latency hides under acc
                j2 = (int)sorted_src[p+2];
                j3 = (int)sorted_src[p+3];
            }
            acc8(a, c0); acc8(a, c1); acc8(a, c2); acc8(a, c3);
        }
        for (int r = 0; r < (cnt & 3); r++){
            int j = (int)sorted_src[p + r];
            uint4 c0 = *(const uint4*)(tbl + (size_t)j*16);
            acc8(a, c0);
        }

        float inv = invdeg[v];
        f32x4 o0, o1;
        #pragma unroll
        for (int i = 0; i < 4; i++){
            float x = a[i]*inv;
            o0[i] = (leaky && x < 0.f) ? 0.2f*x : x;
        }
        #pragma unroll
        for (int i = 0; i < 4; i++){
            float x = a[4+i]*inv;
            o1[i] = (leaky && x < 0.f) ? 0.2f*x : x;
        }
        f32x4* dp = (f32x4*)(dest + (size_t)v*DD + colbase + l4*8);
        __builtin_nontemporal_store(o0, dp);
        __builtin_nontemporal_store(o1, dp+1);
    }
}

// ---------------- final-layer b/s epilogues (expmap0 / l2norm) ----------------
__global__ __launch_bounds__(256)
void k_final(const float* __restrict__ tb, const float* __restrict__ ts,
             float* __restrict__ ob, float* __restrict__ os,
             int n_rows, const float* __restrict__ cptr){
    int wid = (blockIdx.x*256 + threadIdx.x) >> 6;
    if (wid >= n_rows) return;
    int lane = threadIdx.x & 63;
    float2 vb = *(const float2*)(tb + (size_t)wid*DD + lane*2);
    float2 vs = *(const float2*)(ts + (size_t)wid*DD + lane*2);
    float ssb = vb.x*vb.x + vb.y*vb.y;
    float sss = vs.x*vs.x + vs.y*vs.y;
    #pragma unroll
    for (int m = 32; m > 0; m >>= 1){
        ssb += __shfl_xor(ssb, m, 64);
        sss += __shfl_xor(sss, m, 64);
    }
    float cc = cptr[0];
    cc = (cc > 0.f && cc < 1e30f) ? cc : 1.0f;
    float sc = sqrtf(cc);
    float nb = fmaxf(sqrtf(ssb), 1e-10f);
    float scb = tanhf(sc*nb*0.5f) / (sc*nb);
    float scs = 1.0f / fmaxf(sqrtf(sss), 1e-12f);
    *(float2*)(ob + (size_t)wid*DD + lane*2) = make_float2(vb.x*scb, vb.y*scb);
    *(float2*)(os + (size_t)wid*DD + lane*2) = make_float2(vs.x*scs, vs.y*scs);
}

extern "C" void kernel_launch(void* const* d_in, const int* in_sizes, int n_in,
                              void* d_out, int out_size, void* d_ws, size_t ws_size,
                              hipStream_t stream){
    const int*   src = (const int*)d_in[0];
    const int*   dst = (const int*)d_in[1];
    const float* emb_in[3] = {(const float*)d_in[2], (const float*)d_in[3], (const float*)d_in[4]};
    const float* W_in[3]   = {(const float*)d_in[5], (const float*)d_in[7], (const float*)d_in[9]};
    const float* b_in[3]   = {(const float*)d_in[6], (const float*)d_in[8], (const float*)d_in[10]};
    const float* b_c       = (const float*)d_in[11];

    const int E  = in_sizes[0];
    const int ND = in_sizes[2];
    const int N  = ND / DD;
    const int Lnum = in_sizes[5] / (DD*DD);
    const int nw = Lnum*DD*DD;
    const int nchunks = (N + 511) / 512;
    const bool small_idx = (N <= 65535);

    char* w = (char*)d_ws;
    auto alloc = [&](size_t bytes)->char*{
        char* p = w; w += (bytes + 255) & ~(size_t)255; return p;
    };
    u32*   ebS       = (u32*)  alloc((size_t)ND*4);     // 8 shards [N][64B] (e|b)
    u32*   sS        = (u32*)  alloc((size_t)ND*2);     // 4 shards [N][64B] (s)
    float* tb        = (float*)alloc((size_t)ND*4);     // final-layer raw means
    float* ts        = (float*)alloc((size_t)ND*4);
    u16*   Wb[3];
    for (int i = 0; i < 3; i++) Wb[i] = (u16*)alloc((size_t)nw*2);
    float* invdeg    = (float*)alloc((size_t)N*4);
    int*   deg       = (int*)  alloc((size_t)N*4);
    int*   row_ptr   = (int*)  alloc((size_t)(N+1)*4);
    int*   cursor    = (int*)  alloc((size_t)N*4);
    int*   csum      = (int*)  alloc((size_t)nchunks*4);
    void*  sorted_src= (void*) alloc((size_t)E*4);
    (void)ws_size; (void)n_in; (void)out_size;

    float* out_e = (float*)d_out;
    float* out_b = out_e + ND;
    float* out_s = out_e + 2*ND;

    hipMemsetAsync(deg, 0, (size_t)N*4, stream);

    const int TB = 256;
    k_w2b3<<<dim3((nw+TB-1)/TB, 3), TB, 0, stream>>>(W_in[0], W_in[1], W_in[2],
                                                     Wb[0], Wb[1], Wb[2], nw);
    k_hist<<<(E+TB-1)/TB, TB, 0, stream>>>(dst, deg, E);
    k_chunksum<<<nchunks, 256, 0, stream>>>(deg, csum, invdeg, N);
    k_scanchunks<<<1, 256, 0, stream>>>(csum, nchunks, row_ptr, N);
    k_scanwithin<<<nchunks, 256, 0, stream>>>(deg, csum, row_ptr, cursor, N);
    if (small_idx)
        k_fill<u16><<<(E+TB-1)/TB, TB, 0, stream>>>(src, dst, cursor, (u16*)sorted_src, E);
    else
        k_fill<int><<<(E+TB-1)/TB, TB, 0, stream>>>(src, dst, cursor, (int*)sorted_src, E);

    const int gemmblocks = (N + 63) / 64;
    const int NPB = 64*NPG;
    const int nbE = (N + NPB - 1) / NPB;
    const int nbS = (((N + 1) / 2) + NPB - 1) / NPB;
    const int finblocks = (N + 3) / 4;

    const float* se = emb_in[0];
    const float* sb = emb_in[1];
    const float* ss = emb_in[2];

    for (int l = 0; l < Lnum; l++){
        bool last = (l == Lnum - 1);
        if (l == 0)
            k_gemm3<1><<<dim3(gemmblocks, 3), 256, 0, stream>>>(
                se, sb, ss,
                Wb[0] + (size_t)l*DD*DD, Wb[1] + (size_t)l*DD*DD, Wb[2] + (size_t)l*DD*DD,
                b_in[0] + (size_t)l*DD,  b_in[1] + (size_t)l*DD,  b_in[2] + (size_t)l*DD,
                (u16*)ebS, (u16*)sS, N, b_c);
        else
            k_gemm3<0><<<dim3(gemmblocks, 3), 256, 0, stream>>>(
                se, sb, ss,
                Wb[0] + (size_t)l*DD*DD, Wb[1] + (size_t)l*DD*DD, Wb[2] + (size_t)l*DD*DD,
                b_in[0] + (size_t)l*DD,  b_in[1] + (size_t)l*DD,  b_in[2] + (size_t)l*DD,
                (u16*)ebS, (u16*)sS, N, b_c);

        float* dB = last ? tb : out_b;
        float* dS = last ? ts : out_s;
        if (small_idx){
            k_aggT<u16,0><<<8*nbE, 256, 0, stream>>>(ebS, row_ptr, (const u16*)sorted_src,
                                                     invdeg, out_e, dB, dS, N);
            k_aggT<u16,1><<<8*nbS, 256, 0, stream>>>(sS,  row_ptr, (const u16*)sorted_src,
                                                     invdeg, out_e, dB, dS, N);
        } else {
            k_aggT<int,0><<<8*nbE, 256, 0, stream>>>(ebS, row_ptr, (const int*)sorted_src,
                                                     invdeg, out_e, dB, dS, N);
            k_aggT<int,1><<<8*nbS, 256, 0, stream>>>(sS,  row_ptr, (const int*)sorted_src,
                                                     invdeg, out_e, dB, dS, N);
        }
        if (last)
            k_final<<<finblocks, 256, 0, stream>>>(tb, ts, out_b, out_s, N, b_c);

        se = out_e; sb = out_b; ss = out_s;
    }
}

// Round 7
// 471.148 us; speedup vs baseline: 1.3498x; 1.0521x over previous
//
#include <hip/hip_runtime.h>
#include <math.h>

#define DD 128
typedef unsigned int   u32;
typedef unsigned short u16;
typedef short bf16x8 __attribute__((ext_vector_type(8)));
typedef float f32x4  __attribute__((ext_vector_type(4)));

__device__ __forceinline__ float lo2f(u32 p){ return __uint_as_float(p << 16); }
__device__ __forceinline__ float hi2f(u32 p){ return __uint_as_float(p & 0xFFFF0000u); }
__device__ __forceinline__ u16 f2bf(float f){
    u32 u = __float_as_uint(f);
    return (u16)((u + 0x7fffu + ((u >> 16) & 1u)) >> 16);   // RNE
}

// ---------------- CSR build ----------------
__global__ void k_hist(const int* __restrict__ dst, int* __restrict__ deg, int E){
    int i = blockIdx.x*256 + threadIdx.x;
    if (i < E) atomicAdd(&deg[dst[i]], 1);
}

__global__ void k_chunksum(const int* __restrict__ deg, int* __restrict__ csum,
                           float* __restrict__ invdeg, int n){
    __shared__ int sdata[256];
    int t = threadIdx.x;
    int i0 = blockIdx.x*512 + t*2;
    int a = (i0     < n) ? deg[i0]   : 0;
    int b = (i0 + 1 < n) ? deg[i0+1] : 0;
    if (i0     < n) invdeg[i0]   = 1.0f / (float)max(a, 1);
    if (i0 + 1 < n) invdeg[i0+1] = 1.0f / (float)max(b, 1);
    sdata[t] = a + b; __syncthreads();
    for (int off = 128; off > 0; off >>= 1){
        if (t < off) sdata[t] += sdata[t+off];
        __syncthreads();
    }
    if (t == 0) csum[blockIdx.x] = sdata[0];
}

__global__ void k_scanchunks(int* __restrict__ csum, int nchunks,
                             int* __restrict__ row_ptr, int n){
    __shared__ int s[256];
    __shared__ int carry_sh;
    int t = threadIdx.x;
    if (t == 0) carry_sh = 0;
    __syncthreads();
    for (int base = 0; base < nchunks; base += 256){
        int i = base + t;
        int v = (i < nchunks) ? csum[i] : 0;
        s[t] = v;
        __syncthreads();
        for (int off = 1; off < 256; off <<= 1){
            int u = (t >= off) ? s[t-off] : 0;
            __syncthreads();
            s[t] += u;
            __syncthreads();
        }
        int carry = carry_sh;
        int excl  = carry + s[t] - v;
        if (i < nchunks) csum[i] = excl;
        int tot = s[255];
        __syncthreads();
        if (t == 0) carry_sh = carry + tot;
        __syncthreads();
    }
    if (t == 0) row_ptr[n] = carry_sh;
}

__global__ void k_scanwithin(const int* __restrict__ deg, const int* __restrict__ csum,
                             int* __restrict__ row_ptr, int* __restrict__ cursor, int n){
    __shared__ int s[256];
    int t = threadIdx.x;
    int i0 = blockIdx.x*512 + t*2;
    int a = (i0     < n) ? deg[i0]   : 0;
    int b = (i0 + 1 < n) ? deg[i0+1] : 0;
    int tsum = a + b;
    s[t] = tsum; __syncthreads();
    for (int off = 1; off < 256; off <<= 1){
        int v = (t >= off) ? s[t-off] : 0;
        __syncthreads();
        s[t] += v;
        __syncthreads();
    }
    int excl = s[t] - tsum + csum[blockIdx.x];
    if (i0     < n){ row_ptr[i0]   = excl;     cursor[i0]   = excl;     }
    if (i0 + 1 < n){ row_ptr[i0+1] = excl + a; cursor[i0+1] = excl + a; }
}

// IT = u16 when N <= 65535 (halves index fetch + stream pollution), else int.
template<typename IT>
__global__ void k_fill(const int* __restrict__ src, const int* __restrict__ dst,
                       int* __restrict__ cursor, IT* __restrict__ sorted_src, int E){
    int i = blockIdx.x*256 + threadIdx.x;
    if (i < E){
        int p = atomicAdd(&cursor[dst[i]], 1);
        sorted_src[p] = (IT)src[i];
    }
}

__global__ void k_w2b3(const float* __restrict__ w0, const float* __restrict__ w1,
                       const float* __restrict__ w2,
                       u16* __restrict__ o0, u16* __restrict__ o1, u16* __restrict__ o2,
                       int nw){
    int i = blockIdx.x*256 + threadIdx.x;
    if (i >= nw) return;
    const float* s = (blockIdx.y == 0) ? w0 : (blockIdx.y == 1) ? w1 : w2;
    u16*         o = (blockIdx.y == 0) ? o0 : (blockIdx.y == 1) ? o1 : o2;
    o[i] = f2bf(s[i]);
}

// ---------------- MFMA GEMM + fused pre/post transforms ----------------
// PRE : 0 none | 1 logmap0 row-scale | 2 l2norm row-scale
// POST: 0 none | 1 l2norm
// Output SHARD-MAJOR: col (tl*16+m) -> shard (col>>5) at [row*32 + (col&31)].
// TWO 16-row tiles per wave (32 rows): all X loads issued up-front (needs the
// VGPR headroom from __launch_bounds__(256,2)); each B-frag reused for both
// tiles -> half the B traffic, 2x math per wave, half the waves.
template<int PRE, int POST>
__device__ __forceinline__ void gemm_body(const float* __restrict__ X, const u16* __restrict__ Wb,
                                          const float* __restrict__ bias, u16* __restrict__ Y,
                                          size_t sstride, int n_rows, const float* __restrict__ cptr){
    int t = threadIdx.x;
    int wave = t >> 6, lane = t & 63;
    int q = lane >> 4, m = lane & 15;
    int rowbase = blockIdx.x*128 + wave*32;
    int gr0 = min(rowbase + m,      n_rows - 1);
    int gr1 = min(rowbase + 16 + m, n_rows - 1);

    float4 xv0[8], xv1[8];
    const float4* xp0 = (const float4*)(X + (size_t)gr0*DD);
    const float4* xp1 = (const float4*)(X + (size_t)gr1*DD);
    #pragma unroll
    for (int c = 0; c < 4; c++){
        xv0[2*c]   = xp0[c*8 + q*2];
        xv0[2*c+1] = xp0[c*8 + q*2 + 1];
        xv1[2*c]   = xp1[c*8 + q*2];
        xv1[2*c+1] = xp1[c*8 + q*2 + 1];
    }

    float scale0 = 1.0f, scale1 = 1.0f;
    if (PRE != 0){
        float ss0 = 0.f, ss1 = 0.f;
        #pragma unroll
        for (int i = 0; i < 8; i++){
            ss0 += xv0[i].x*xv0[i].x + xv0[i].y*xv0[i].y + xv0[i].z*xv0[i].z + xv0[i].w*xv0[i].w;
            ss1 += xv1[i].x*xv1[i].x + xv1[i].y*xv1[i].y + xv1[i].z*xv1[i].z + xv1[i].w*xv1[i].w;
        }
        ss0 += __shfl_xor(ss0, 16, 64); ss0 += __shfl_xor(ss0, 32, 64);
        ss1 += __shfl_xor(ss1, 16, 64); ss1 += __shfl_xor(ss1, 32, 64);
        if (PRE == 1){
            float c  = cptr[0];
            c = (c > 0.f && c < 1e30f) ? c : 1.0f;
            float sc = sqrtf(c);
            float n0 = fmaxf(sqrtf(ss0), 1e-10f);
            float n1 = fmaxf(sqrtf(ss1), 1e-10f);
            float a0 = fminf(sc*n0, 0.99999994f);
            float a1 = fminf(sc*n1, 0.99999994f);
            scale0 = (2.0f/sc) * atanhf(a0) / n0;
            scale1 = (2.0f/sc) * atanhf(a1) / n1;
        } else {
            scale0 = 1.0f / fmaxf(sqrtf(ss0), 1e-12f);
            scale1 = 1.0f / fmaxf(sqrtf(ss1), 1e-12f);
        }
    }

    bf16x8 af0[4], af1[4];
    #pragma unroll
    for (int c = 0; c < 4; c++){
        const float* xf0 = (const float*)&xv0[2*c];
        const float* xf1 = (const float*)&xv1[2*c];
        #pragma unroll
        for (int j = 0; j < 8; j++){
            af0[c][j] = (short)f2bf(xf0[j]*scale0);
            af1[c][j] = (short)f2bf(xf1[j]*scale1);
        }
    }

    f32x4 acc0[8], acc1[8];
    #pragma unroll
    for (int tl = 0; tl < 8; tl++){
        acc0[tl] = (f32x4){0.f,0.f,0.f,0.f};
        acc1[tl] = (f32x4){0.f,0.f,0.f,0.f};
    }

    const u16* wb = Wb + (size_t)m*DD + q*8;
    #pragma unroll
    for (int c = 0; c < 4; c++){
        #pragma unroll
        for (int tl = 0; tl < 8; tl++){
            bf16x8 bfr = *(const bf16x8*)(wb + (size_t)tl*16*DD + c*32);
            acc0[tl] = __builtin_amdgcn_mfma_f32_16x16x32_bf16(af0[c], bfr, acc0[tl], 0, 0, 0);
            acc1[tl] = __builtin_amdgcn_mfma_f32_16x16x32_bf16(af1[c], bfr, acc1[tl], 0, 0, 0);
        }
    }

    #pragma unroll
    for (int tl = 0; tl < 8; tl++){
        float bv = bias[tl*16 + m];
        #pragma unroll
        for (int r = 0; r < 4; r++){ acc0[tl][r] += bv; acc1[tl][r] += bv; }
    }
    if (POST == 1){
        float ssr0[4] = {0.f,0.f,0.f,0.f};
        float ssr1[4] = {0.f,0.f,0.f,0.f};
        #pragma unroll
        for (int tl = 0; tl < 8; tl++)
            #pragma unroll
            for (int r = 0; r < 4; r++){
                ssr0[r] += acc0[tl][r]*acc0[tl][r];
                ssr1[r] += acc1[tl][r]*acc1[tl][r];
            }
        #pragma unroll
        for (int r = 0; r < 4; r++){
            float s0 = ssr0[r], s1 = ssr1[r];
            s0 += __shfl_xor(s0, 1, 64); s0 += __shfl_xor(s0, 2, 64);
            s0 += __shfl_xor(s0, 4, 64); s0 += __shfl_xor(s0, 8, 64);
            s1 += __shfl_xor(s1, 1, 64); s1 += __shfl_xor(s1, 2, 64);
            s1 += __shfl_xor(s1, 4, 64); s1 += __shfl_xor(s1, 8, 64);
            float k0 = 1.0f / fmaxf(sqrtf(s0), 1e-12f);
            float k1 = 1.0f / fmaxf(sqrtf(s1), 1e-12f);
            #pragma unroll
            for (int tl = 0; tl < 8; tl++){ acc0[tl][r] *= k0; acc1[tl][r] *= k1; }
        }
    }
    #pragma unroll
    for (int r = 0; r < 4; r++){
        int grow0 = rowbase + q*4 + r;
        int grow1 = rowbase + 16 + q*4 + r;
        if (grow0 < n_rows){
            #pragma unroll
            for (int tl = 0; tl < 8; tl++)
                Y[(size_t)(tl>>1)*sstride + (size_t)grow0*32 + (tl&1)*16 + m] = f2bf(acc0[tl][r]);
        }
        if (grow1 < n_rows){
            #pragma unroll
            for (int tl = 0; tl < 8; tl++)
                Y[(size_t)(tl>>1)*sstride + (size_t)grow1*32 + (tl&1)*16 + m] = f2bf(acc1[tl][r]);
        }
    }
}

// PREB: layer0 = 1 (logmap0 on ball input), later layers = 0 (identity:
// log_map(0, exp_map(0, v)) == v). e -> ebS shards 0-3, b -> ebS shards 4-7,
// s -> sS shards 0-3 (l2norm idempotent).
template<int PREB>
__global__ __launch_bounds__(256, 2)
void k_gemm3(const float* __restrict__ Xe, const float* __restrict__ Xb, const float* __restrict__ Xs,
             const u16* __restrict__ We, const u16* __restrict__ Wh, const u16* __restrict__ Ws,
             const float* __restrict__ be, const float* __restrict__ bb, const float* __restrict__ bs,
             u16* __restrict__ ebS, u16* __restrict__ sS,
             int n_rows, const float* __restrict__ cptr){
    size_t sstride = (size_t)n_rows * 32;
    if (blockIdx.y == 0)      gemm_body<0,0>(Xe, We, be, ebS,            sstride, n_rows, cptr);
    else if (blockIdx.y == 1) gemm_body<PREB,0>(Xb, Wh, bb, ebS+4*sstride, sstride, n_rows, cptr);
    else                      gemm_body<2,1>(Xs, Ws, bs, sS,             sstride, n_rows, cptr);
}

// ---------------- XCD-sharded aggregation, shard-contiguous tables --------
// Shard-major tables: 12 shards of [N][64B]. Per-XCD resident set = ONE shard
// (3.2MB < 4MiB L2). MODE 0 (eb): shard = xcd over 8, all nodes. MODE 1 (s):
// shard = xcd&3, node-half = xcd>>2. Two SEQUENTIAL dispatches so eb and s
// shards never share an XCD's L2.
// Wave = 16 groups x 4 lanes: group owns a node, lane owns a 16B slice.
// Edge loop: 4-deep gathers + next-quad index prefetch rotation.
#define NPG 2              // nodes per group per block (block covers 64*NPG)
__device__ __forceinline__ void acc8(float* a, uint4 p){
    a[0] += lo2f(p.x); a[1] += hi2f(p.x);
    a[2] += lo2f(p.y); a[3] += hi2f(p.y);
    a[4] += lo2f(p.z); a[5] += hi2f(p.z);
    a[6] += lo2f(p.w); a[7] += hi2f(p.w);
}

template<typename IT, int MODE>
__global__ __launch_bounds__(256)
void k_aggT(const u32* __restrict__ tab,
            const int* __restrict__ row_ptr, const IT* __restrict__ sorted_src,
            const float* __restrict__ invdeg,
            float* __restrict__ oE, float* __restrict__ oB, float* __restrict__ oS,
            int n_rows){
    const int NPB = 64*NPG;
    int xcd = blockIdx.x & 7;
    int idx = blockIdx.x >> 3;
    size_t sstride = (size_t)n_rows * 16;      // u32 per shard

    const u32* shard; float* dest; int nodebase, hi, colbase; bool leaky;
    if (MODE == 0){
        shard = tab + (size_t)xcd * sstride;   // eb shard 0..7
        dest = (xcd < 4) ? oE : oB;
        leaky = (xcd < 4);
        colbase = (xcd & 3) * 32;
        nodebase = idx * NPB; hi = n_rows;
        if (nodebase >= hi) return;
    } else {
        int half = xcd >> 2, c = xcd & 3;      // s shard 0..3, node half
        int lo  = (int)(((long long)n_rows * half) >> 1);
        int hi2 = (int)(((long long)n_rows * (half+1)) >> 1);
        shard = tab + (size_t)c * sstride;
        dest = oS; leaky = false;
        colbase = c * 32;
        nodebase = lo + idx*NPB; hi = hi2;
        if (nodebase >= hi) return;
    }

    int grp = threadIdx.x >> 2;                // 0..63, one node per group
    int l4  = threadIdx.x & 3;                 // 16B column slice
    const u32* tbl = shard + l4*4;

    #pragma unroll
    for (int k = 0; k < NPG; k++){
        int v = nodebase + k*64 + grp;         // consecutive groups -> consec nodes
        if (v >= hi) continue;
        int beg = row_ptr[v], end = row_ptr[v+1];
        int cnt = end - beg;
        float a[8];
        #pragma unroll
        for (int i = 0; i < 8; i++) a[i] = 0.f;

        int nq = cnt >> 2;
        int p = beg;
        int j0 = 0, j1 = 0, j2 = 0, j3 = 0;
        if (nq > 0){
            j0 = (int)sorted_src[p]; j1 = (int)sorted_src[p+1];
            j2 = (int)sorted_src[p+2]; j3 = (int)sorted_src[p+3];
        }
        for (int q = 0; q < nq; q++){
            uint4 c0 = *(const uint4*)(tbl + (size_t)j0*16);
            uint4 c1 = *(const uint4*)(tbl + (size_t)j1*16);
            uint4 c2 = *(const uint4*)(tbl + (size_t)j2*16);
            uint4 c3 = *(const uint4*)(tbl + (size_t)j3*16);
            p += 4;
            if (q + 1 < nq){                   // prefetch next quad's indices
                j0 = (int)sorted_src[p];
                j1 = (int)sorted_src[p+1];
                j2 = (int)sorted_src[p+2];
                j3 = (int)sorted_src[p+3];
            }
            acc8(a, c0); acc8(a, c1); acc8(a, c2); acc8(a, c3);
        }
        for (int r = 0; r < (cnt & 3); r++){
            int j = (int)sorted_src[p + r];
            uint4 c0 = *(const uint4*)(tbl + (size_t)j*16);
            acc8(a, c0);
        }

        float inv = invdeg[v];
        f32x4 o0, o1;
        #pragma unroll
        for (int i = 0; i < 4; i++){
            float x = a[i]*inv;
            o0[i] = (leaky && x < 0.f) ? 0.2f*x : x;
        }
        #pragma unroll
        for (int i = 0; i < 4; i++){
            float x = a[4+i]*inv;
            o1[i] = (leaky && x < 0.f) ? 0.2f*x : x;
        }
        f32x4* dp = (f32x4*)(dest + (size_t)v*DD + colbase + l4*8);
        __builtin_nontemporal_store(o0, dp);
        __builtin_nontemporal_store(o1, dp+1);
    }
}

// ---------------- final-layer b/s epilogues (expmap0 / l2norm) ----------------
__global__ __launch_bounds__(256)
void k_final(const float* __restrict__ tb, const float* __restrict__ ts,
             float* __restrict__ ob, float* __restrict__ os,
             int n_rows, const float* __restrict__ cptr){
    int wid = (blockIdx.x*256 + threadIdx.x) >> 6;
    if (wid >= n_rows) return;
    int lane = threadIdx.x & 63;
    float2 vb = *(const float2*)(tb + (size_t)wid*DD + lane*2);
    float2 vs = *(const float2*)(ts + (size_t)wid*DD + lane*2);
    float ssb = vb.x*vb.x + vb.y*vb.y;
    float sss = vs.x*vs.x + vs.y*vs.y;
    #pragma unroll
    for (int m = 32; m > 0; m >>= 1){
        ssb += __shfl_xor(ssb, m, 64);
        sss += __shfl_xor(sss, m, 64);
    }
    float cc = cptr[0];
    cc = (cc > 0.f && cc < 1e30f) ? cc : 1.0f;
    float sc = sqrtf(cc);
    float nb = fmaxf(sqrtf(ssb), 1e-10f);
    float scb = tanhf(sc*nb*0.5f) / (sc*nb);
    float scs = 1.0f / fmaxf(sqrtf(sss), 1e-12f);
    *(float2*)(ob + (size_t)wid*DD + lane*2) = make_float2(vb.x*scb, vb.y*scb);
    *(float2*)(os + (size_t)wid*DD + lane*2) = make_float2(vs.x*scs, vs.y*scs);
}

extern "C" void kernel_launch(void* const* d_in, const int* in_sizes, int n_in,
                              void* d_out, int out_size, void* d_ws, size_t ws_size,
                              hipStream_t stream){
    const int*   src = (const int*)d_in[0];
    const int*   dst = (const int*)d_in[1];
    const float* emb_in[3] = {(const float*)d_in[2], (const float*)d_in[3], (const float*)d_in[4]};
    const float* W_in[3]   = {(const float*)d_in[5], (const float*)d_in[7], (const float*)d_in[9]};
    const float* b_in[3]   = {(const float*)d_in[6], (const float*)d_in[8], (const float*)d_in[10]};
    const float* b_c       = (const float*)d_in[11];

    const int E  = in_sizes[0];
    const int ND = in_sizes[2];
    const int N  = ND / DD;
    const int Lnum = in_sizes[5] / (DD*DD);
    const int nw = Lnum*DD*DD;
    const int nchunks = (N + 511) / 512;
    const bool small_idx = (N <= 65535);

    char* w = (char*)d_ws;
    auto alloc = [&](size_t bytes)->char*{
        char* p = w; w += (bytes + 255) & ~(size_t)255; return p;
    };
    u32*   ebS       = (u32*)  alloc((size_t)ND*4);     // 8 shards [N][64B] (e|b)
    u32*   sS        = (u32*)  alloc((size_t)ND*2);     // 4 shards [N][64B] (s)
    float* tb        = (float*)alloc((size_t)ND*4);     // final-layer raw means
    float* ts        = (float*)alloc((size_t)ND*4);
    u16*   Wb[3];
    for (int i = 0; i < 3; i++) Wb[i] = (u16*)alloc((size_t)nw*2);
    float* invdeg    = (float*)alloc((size_t)N*4);
    int*   deg       = (int*)  alloc((size_t)N*4);
    int*   row_ptr   = (int*)  alloc((size_t)(N+1)*4);
    int*   cursor    = (int*)  alloc((size_t)N*4);
    int*   csum      = (int*)  alloc((size_t)nchunks*4);
    void*  sorted_src= (void*) alloc((size_t)E*4);
    (void)ws_size; (void)n_in; (void)out_size;

    float* out_e = (float*)d_out;
    float* out_b = out_e + ND;
    float* out_s = out_e + 2*ND;

    hipMemsetAsync(deg, 0, (size_t)N*4, stream);

    const int TB = 256;
    k_w2b3<<<dim3((nw+TB-1)/TB, 3), TB, 0, stream>>>(W_in[0], W_in[1], W_in[2],
                                                     Wb[0], Wb[1], Wb[2], nw);
    k_hist<<<(E+TB-1)/TB, TB, 0, stream>>>(dst, deg, E);
    k_chunksum<<<nchunks, 256, 0, stream>>>(deg, csum, invdeg, N);
    k_scanchunks<<<1, 256, 0, stream>>>(csum, nchunks, row_ptr, N);
    k_scanwithin<<<nchunks, 256, 0, stream>>>(deg, csum, row_ptr, cursor, N);
    if (small_idx)
        k_fill<u16><<<(E+TB-1)/TB, TB, 0, stream>>>(src, dst, cursor, (u16*)sorted_src, E);
    else
        k_fill<int><<<(E+TB-1)/TB, TB, 0, stream>>>(src, dst, cursor, (int*)sorted_src, E);

    const int gemmblocks = (N + 127) / 128;
    const int NPB = 64*NPG;
    const int nbE = (N + NPB - 1) / NPB;
    const int nbS = (((N + 1) / 2) + NPB - 1) / NPB;
    const int finblocks = (N + 3) / 4;

    const float* se = emb_in[0];
    const float* sb = emb_in[1];
    const float* ss = emb_in[2];

    for (int l = 0; l < Lnum; l++){
        bool last = (l == Lnum - 1);
        if (l == 0)
            k_gemm3<1><<<dim3(gemmblocks, 3), 256, 0, stream>>>(
                se, sb, ss,
                Wb[0] + (size_t)l*DD*DD, Wb[1] + (size_t)l*DD*DD, Wb[2] + (size_t)l*DD*DD,
                b_in[0] + (size_t)l*DD,  b_in[1] + (size_t)l*DD,  b_in[2] + (size_t)l*DD,
                (u16*)ebS, (u16*)sS, N, b_c);
        else
            k_gemm3<0><<<dim3(gemmblocks, 3), 256, 0, stream>>>(
                se, sb, ss,
                Wb[0] + (size_t)l*DD*DD, Wb[1] + (size_t)l*DD*DD, Wb[2] + (size_t)l*DD*DD,
                b_in[0] + (size_t)l*DD,  b_in[1] + (size_t)l*DD,  b_in[2] + (size_t)l*DD,
                (u16*)ebS, (u16*)sS, N, b_c);

        float* dB = last ? tb : out_b;
        float* dS = last ? ts : out_s;
        if (small_idx){
            k_aggT<u16,0><<<8*nbE, 256, 0, stream>>>(ebS, row_ptr, (const u16*)sorted_src,
                                                     invdeg, out_e, dB, dS, N);
            k_aggT<u16,1><<<8*nbS, 256, 0, stream>>>(sS,  row_ptr, (const u16*)sorted_src,
                                                     invdeg, out_e, dB, dS, N);
        } else {
            k_aggT<int,0><<<8*nbE, 256, 0, stream>>>(ebS, row_ptr, (const int*)sorted_src,
                                                     invdeg, out_e, dB, dS, N);
            k_aggT<int,1><<<8*nbS, 256, 0, stream>>>(sS,  row_ptr, (const int*)sorted_src,
                                                     invdeg, out_e, dB, dS, N);
        }
        if (last)
            k_final<<<finblocks, 256, 0, stream>>>(tb, ts, out_b, out_s, N, b_c);

        se = out_e; sb = out_b; ss = out_s;
    }
}

// Round 8
// 464.142 us; speedup vs baseline: 1.3702x; 1.0151x over previous
//
#include <hip/hip_runtime.h>
#include <math.h>

#define DD 128
typedef unsigned int   u32;
typedef unsigned short u16;
typedef short bf16x8 __attribute__((ext_vector_type(8)));
typedef float f32x4  __attribute__((ext_vector_type(4)));
typedef u32   u32x4v __attribute__((ext_vector_type(4)));

__device__ __forceinline__ float lo2f(u32 p){ return __uint_as_float(p << 16); }
__device__ __forceinline__ float hi2f(u32 p){ return __uint_as_float(p & 0xFFFF0000u); }
__device__ __forceinline__ float b2f(u16 b){ return __uint_as_float(((u32)b) << 16); }
__device__ __forceinline__ u16 f2bf(float f){
    u32 u = __float_as_uint(f);
    return (u16)((u + 0x7fffu + ((u >> 16) & 1u)) >> 16);   // RNE
}

// ---------------- CSR build ----------------
__global__ void k_hist(const int* __restrict__ dst, int* __restrict__ deg, int E){
    int i = blockIdx.x*256 + threadIdx.x;
    if (i < E) atomicAdd(&deg[dst[i]], 1);
}

__global__ void k_chunksum(const int* __restrict__ deg, int* __restrict__ csum,
                           float* __restrict__ invdeg, int n){
    __shared__ int sdata[256];
    int t = threadIdx.x;
    int i0 = blockIdx.x*512 + t*2;
    int a = (i0     < n) ? deg[i0]   : 0;
    int b = (i0 + 1 < n) ? deg[i0+1] : 0;
    if (i0     < n) invdeg[i0]   = 1.0f / (float)max(a, 1);
    if (i0 + 1 < n) invdeg[i0+1] = 1.0f / (float)max(b, 1);
    sdata[t] = a + b; __syncthreads();
    for (int off = 128; off > 0; off >>= 1){
        if (t < off) sdata[t] += sdata[t+off];
        __syncthreads();
    }
    if (t == 0) csum[blockIdx.x] = sdata[0];
}

__global__ void k_scanchunks(int* __restrict__ csum, int nchunks,
                             int* __restrict__ row_ptr, int n){
    __shared__ int s[256];
    __shared__ int carry_sh;
    int t = threadIdx.x;
    if (t == 0) carry_sh = 0;
    __syncthreads();
    for (int base = 0; base < nchunks; base += 256){
        int i = base + t;
        int v = (i < nchunks) ? csum[i] : 0;
        s[t] = v;
        __syncthreads();
        for (int off = 1; off < 256; off <<= 1){
            int u = (t >= off) ? s[t-off] : 0;
            __syncthreads();
            s[t] += u;
            __syncthreads();
        }
        int carry = carry_sh;
        int excl  = carry + s[t] - v;
        if (i < nchunks) csum[i] = excl;
        int tot = s[255];
        __syncthreads();
        if (t == 0) carry_sh = carry + tot;
        __syncthreads();
    }
    if (t == 0) row_ptr[n] = carry_sh;
}

__global__ void k_scanwithin(const int* __restrict__ deg, const int* __restrict__ csum,
                             int* __restrict__ row_ptr, int* __restrict__ cursor, int n){
    __shared__ int s[256];
    int t = threadIdx.x;
    int i0 = blockIdx.x*512 + t*2;
    int a = (i0     < n) ? deg[i0]   : 0;
    int b = (i0 + 1 < n) ? deg[i0+1] : 0;
    int tsum = a + b;
    s[t] = tsum; __syncthreads();
    for (int off = 1; off < 256; off <<= 1){
        int v = (t >= off) ? s[t-off] : 0;
        __syncthreads();
        s[t] += v;
        __syncthreads();
    }
    int excl = s[t] - tsum + csum[blockIdx.x];
    if (i0     < n){ row_ptr[i0]   = excl;     cursor[i0]   = excl;     }
    if (i0 + 1 < n){ row_ptr[i0+1] = excl + a; cursor[i0+1] = excl + a; }
}

// IT = u16 when N <= 65535 (halves index fetch + stream pollution), else int.
template<typename IT>
__global__ void k_fill(const int* __restrict__ src, const int* __restrict__ dst,
                       int* __restrict__ cursor, IT* __restrict__ sorted_src, int E){
    int i = blockIdx.x*256 + threadIdx.x;
    if (i < E){
        int p = atomicAdd(&cursor[dst[i]], 1);
        sorted_src[p] = (IT)src[i];
    }
}

__global__ void k_w2b3(const float* __restrict__ w0, const float* __restrict__ w1,
                       const float* __restrict__ w2,
                       u16* __restrict__ o0, u16* __restrict__ o1, u16* __restrict__ o2,
                       int nw){
    int i = blockIdx.x*256 + threadIdx.x;
    if (i >= nw) return;
    const float* s = (blockIdx.y == 0) ? w0 : (blockIdx.y == 1) ? w1 : w2;
    u16*         o = (blockIdx.y == 0) ? o0 : (blockIdx.y == 1) ? o1 : o2;
    o[i] = f2bf(s[i]);
}

// ---------------- shared GEMM epilogue (bias, optional l2norm, shard store) --
template<int POST>
__device__ __forceinline__ void gemm_epi(f32x4* acc0, f32x4* acc1,
                                         const float* __restrict__ bias, u16* __restrict__ Y,
                                         size_t sstride, int n_rows,
                                         int rowbase, int q, int m){
    #pragma unroll
    for (int tl = 0; tl < 8; tl++){
        float bv = bias[tl*16 + m];
        #pragma unroll
        for (int r = 0; r < 4; r++){ acc0[tl][r] += bv; acc1[tl][r] += bv; }
    }
    if (POST == 1){
        float ssr0[4] = {0.f,0.f,0.f,0.f};
        float ssr1[4] = {0.f,0.f,0.f,0.f};
        #pragma unroll
        for (int tl = 0; tl < 8; tl++)
            #pragma unroll
            for (int r = 0; r < 4; r++){
                ssr0[r] += acc0[tl][r]*acc0[tl][r];
                ssr1[r] += acc1[tl][r]*acc1[tl][r];
            }
        #pragma unroll
        for (int r = 0; r < 4; r++){
            float s0 = ssr0[r], s1 = ssr1[r];
            s0 += __shfl_xor(s0, 1, 64); s0 += __shfl_xor(s0, 2, 64);
            s0 += __shfl_xor(s0, 4, 64); s0 += __shfl_xor(s0, 8, 64);
            s1 += __shfl_xor(s1, 1, 64); s1 += __shfl_xor(s1, 2, 64);
            s1 += __shfl_xor(s1, 4, 64); s1 += __shfl_xor(s1, 8, 64);
            float k0 = 1.0f / fmaxf(sqrtf(s0), 1e-12f);
            float k1 = 1.0f / fmaxf(sqrtf(s1), 1e-12f);
            #pragma unroll
            for (int tl = 0; tl < 8; tl++){ acc0[tl][r] *= k0; acc1[tl][r] *= k1; }
        }
    }
    #pragma unroll
    for (int r = 0; r < 4; r++){
        int grow0 = rowbase + q*4 + r;
        int grow1 = rowbase + 16 + q*4 + r;
        if (grow0 < n_rows){
            #pragma unroll
            for (int tl = 0; tl < 8; tl++)
                Y[(size_t)(tl>>1)*sstride + (size_t)grow0*32 + (tl&1)*16 + m] = f2bf(acc0[tl][r]);
        }
        if (grow1 < n_rows){
            #pragma unroll
            for (int tl = 0; tl < 8; tl++)
                Y[(size_t)(tl>>1)*sstride + (size_t)grow1*32 + (tl&1)*16 + m] = f2bf(acc1[tl][r]);
        }
    }
}

// ---------------- MFMA GEMM, fp32 X (layer 0: external inputs) ----------------
// PRE : 0 none | 1 logmap0 row-scale | 2 l2norm row-scale. POST: 0|1 l2norm.
// Output SHARD-MAJOR: col (tl*16+m) -> shard (col>>5) at [row*32 + (col&31)].
// Two 16-row tiles per wave; B-frag reused for both.
template<int PRE, int POST>
__device__ __forceinline__ void gemm_body(const float* __restrict__ X, const u16* __restrict__ Wb,
                                          const float* __restrict__ bias, u16* __restrict__ Y,
                                          size_t sstride, int n_rows, const float* __restrict__ cptr){
    int t = threadIdx.x;
    int wave = t >> 6, lane = t & 63;
    int q = lane >> 4, m = lane & 15;
    int rowbase = blockIdx.x*128 + wave*32;
    int gr0 = min(rowbase + m,      n_rows - 1);
    int gr1 = min(rowbase + 16 + m, n_rows - 1);

    float4 xv0[8], xv1[8];
    const float4* xp0 = (const float4*)(X + (size_t)gr0*DD);
    const float4* xp1 = (const float4*)(X + (size_t)gr1*DD);
    #pragma unroll
    for (int c = 0; c < 4; c++){
        xv0[2*c]   = xp0[c*8 + q*2];
        xv0[2*c+1] = xp0[c*8 + q*2 + 1];
        xv1[2*c]   = xp1[c*8 + q*2];
        xv1[2*c+1] = xp1[c*8 + q*2 + 1];
    }

    float scale0 = 1.0f, scale1 = 1.0f;
    if (PRE != 0){
        float ss0 = 0.f, ss1 = 0.f;
        #pragma unroll
        for (int i = 0; i < 8; i++){
            ss0 += xv0[i].x*xv0[i].x + xv0[i].y*xv0[i].y + xv0[i].z*xv0[i].z + xv0[i].w*xv0[i].w;
            ss1 += xv1[i].x*xv1[i].x + xv1[i].y*xv1[i].y + xv1[i].z*xv1[i].z + xv1[i].w*xv1[i].w;
        }
        ss0 += __shfl_xor(ss0, 16, 64); ss0 += __shfl_xor(ss0, 32, 64);
        ss1 += __shfl_xor(ss1, 16, 64); ss1 += __shfl_xor(ss1, 32, 64);
        if (PRE == 1){
            float c  = cptr[0];
            c = (c > 0.f && c < 1e30f) ? c : 1.0f;
            float sc = sqrtf(c);
            float n0 = fmaxf(sqrtf(ss0), 1e-10f);
            float n1 = fmaxf(sqrtf(ss1), 1e-10f);
            float a0 = fminf(sc*n0, 0.99999994f);
            float a1 = fminf(sc*n1, 0.99999994f);
            scale0 = (2.0f/sc) * atanhf(a0) / n0;
            scale1 = (2.0f/sc) * atanhf(a1) / n1;
        } else {
            scale0 = 1.0f / fmaxf(sqrtf(ss0), 1e-12f);
            scale1 = 1.0f / fmaxf(sqrtf(ss1), 1e-12f);
        }
    }

    bf16x8 af0[4], af1[4];
    #pragma unroll
    for (int c = 0; c < 4; c++){
        const float* xf0 = (const float*)&xv0[2*c];
        const float* xf1 = (const float*)&xv1[2*c];
        #pragma unroll
        for (int j = 0; j < 8; j++){
            af0[c][j] = (short)f2bf(xf0[j]*scale0);
            af1[c][j] = (short)f2bf(xf1[j]*scale1);
        }
    }

    f32x4 acc0[8], acc1[8];
    #pragma unroll
    for (int tl = 0; tl < 8; tl++){
        acc0[tl] = (f32x4){0.f,0.f,0.f,0.f};
        acc1[tl] = (f32x4){0.f,0.f,0.f,0.f};
    }
    const u16* wb = Wb + (size_t)m*DD + q*8;
    #pragma unroll
    for (int c = 0; c < 4; c++){
        #pragma unroll
        for (int tl = 0; tl < 8; tl++){
            bf16x8 bfr = *(const bf16x8*)(wb + (size_t)tl*16*DD + c*32);
            acc0[tl] = __builtin_amdgcn_mfma_f32_16x16x32_bf16(af0[c], bfr, acc0[tl], 0, 0, 0);
            acc1[tl] = __builtin_amdgcn_mfma_f32_16x16x32_bf16(af1[c], bfr, acc1[tl], 0, 0, 0);
        }
    }
    gemm_epi<POST>(acc0, acc1, bias, Y, sstride, n_rows, rowbase, q, m);
}

// ---------------- MFMA GEMM, bf16 X (layers >= 1: intermediate states) -------
// PRE=0: af fragments ARE the loaded bits (zero conversion VALU, half the
// X bytes of the fp32 path). PRE=2 (s): norm from bf16 values (divided out).
template<int PRE, int POST>
__device__ __forceinline__ void gemm_bodyB(const u16* __restrict__ X, const u16* __restrict__ Wb,
                                           const float* __restrict__ bias, u16* __restrict__ Y,
                                           size_t sstride, int n_rows){
    int t = threadIdx.x;
    int wave = t >> 6, lane = t & 63;
    int q = lane >> 4, m = lane & 15;
    int rowbase = blockIdx.x*128 + wave*32;
    int gr0 = min(rowbase + m,      n_rows - 1);
    int gr1 = min(rowbase + 16 + m, n_rows - 1);

    bf16x8 af0[4], af1[4];
    const u16* xr0 = X + (size_t)gr0*DD + q*8;
    const u16* xr1 = X + (size_t)gr1*DD + q*8;
    #pragma unroll
    for (int c = 0; c < 4; c++){
        af0[c] = *(const bf16x8*)(xr0 + c*32);
        af1[c] = *(const bf16x8*)(xr1 + c*32);
    }

    if (PRE == 2){
        float x0[32], x1[32];
        float ss0 = 0.f, ss1 = 0.f;
        #pragma unroll
        for (int c = 0; c < 4; c++)
            #pragma unroll
            for (int j = 0; j < 8; j++){
                float f0 = b2f((u16)af0[c][j]);
                float f1 = b2f((u16)af1[c][j]);
                x0[c*8+j] = f0; x1[c*8+j] = f1;
                ss0 += f0*f0; ss1 += f1*f1;
            }
        ss0 += __shfl_xor(ss0, 16, 64); ss0 += __shfl_xor(ss0, 32, 64);
        ss1 += __shfl_xor(ss1, 16, 64); ss1 += __shfl_xor(ss1, 32, 64);
        float k0 = 1.0f / fmaxf(sqrtf(ss0), 1e-12f);
        float k1 = 1.0f / fmaxf(sqrtf(ss1), 1e-12f);
        #pragma unroll
        for (int c = 0; c < 4; c++)
            #pragma unroll
            for (int j = 0; j < 8; j++){
                af0[c][j] = (short)f2bf(x0[c*8+j]*k0);
                af1[c][j] = (short)f2bf(x1[c*8+j]*k1);
            }
    }

    f32x4 acc0[8], acc1[8];
    #pragma unroll
    for (int tl = 0; tl < 8; tl++){
        acc0[tl] = (f32x4){0.f,0.f,0.f,0.f};
        acc1[tl] = (f32x4){0.f,0.f,0.f,0.f};
    }
    const u16* wb = Wb + (size_t)m*DD + q*8;
    #pragma unroll
    for (int c = 0; c < 4; c++){
        #pragma unroll
        for (int tl = 0; tl < 8; tl++){
            bf16x8 bfr = *(const bf16x8*)(wb + (size_t)tl*16*DD + c*32);
            acc0[tl] = __builtin_amdgcn_mfma_f32_16x16x32_bf16(af0[c], bfr, acc0[tl], 0, 0, 0);
            acc1[tl] = __builtin_amdgcn_mfma_f32_16x16x32_bf16(af1[c], bfr, acc1[tl], 0, 0, 0);
        }
    }
    gemm_epi<POST>(acc0, acc1, bias, Y, sstride, n_rows, rowbase, q, m);
}

// layer 0: fp32 external inputs; b gets logmap0 (PRE=1)
__global__ __launch_bounds__(256, 2)
void k_gemm3(const float* __restrict__ Xe, const float* __restrict__ Xb, const float* __restrict__ Xs,
             const u16* __restrict__ We, const u16* __restrict__ Wh, const u16* __restrict__ Ws,
             const float* __restrict__ be, const float* __restrict__ bb, const float* __restrict__ bs,
             u16* __restrict__ ebS, u16* __restrict__ sS,
             int n_rows, const float* __restrict__ cptr){
    size_t sstride = (size_t)n_rows * 32;
    if (blockIdx.y == 0)      gemm_body<0,0>(Xe, We, be, ebS,            sstride, n_rows, cptr);
    else if (blockIdx.y == 1) gemm_body<1,0>(Xb, Wh, bb, ebS+4*sstride, sstride, n_rows, cptr);
    else                      gemm_body<2,1>(Xs, Ws, bs, sS,             sstride, n_rows, cptr);
}

// layers >= 1: bf16 intermediates; b is identity (log∘exp cancels)
__global__ __launch_bounds__(256, 2)
void k_gemm3b(const u16* __restrict__ Xe, const u16* __restrict__ Xb, const u16* __restrict__ Xs,
              const u16* __restrict__ We, const u16* __restrict__ Wh, const u16* __restrict__ Ws,
              const float* __restrict__ be, const float* __restrict__ bb, const float* __restrict__ bs,
              u16* __restrict__ ebS, u16* __restrict__ sS, int n_rows){
    size_t sstride = (size_t)n_rows * 32;
    if (blockIdx.y == 0)      gemm_bodyB<0,0>(Xe, We, be, ebS,            sstride, n_rows);
    else if (blockIdx.y == 1) gemm_bodyB<0,0>(Xb, Wh, bb, ebS+4*sstride, sstride, n_rows);
    else                      gemm_bodyB<2,1>(Xs, Ws, bs, sS,             sstride, n_rows);
}

// ---------------- XCD-sharded aggregation, shard-contiguous tables --------
// Shard-major tables: 12 shards of [N][64B]. Per-XCD resident set = ONE shard
// (3.2MB < 4MiB L2). MODE 0 (eb): shard = xcd, all nodes. MODE 1 (s):
// shard = xcd&3, node-half = xcd>>2. Sequential dispatches (no L2 sharing).
// Wave = 16 groups x 4 lanes; group owns a node, lane owns a 16B slice.
// OB=1: bf16 NT store (intermediate layers); OB=0: fp32 NT store (final).
#define NPG 2              // nodes per group per block (block covers 64*NPG)
__device__ __forceinline__ void acc8(float* a, uint4 p){
    a[0] += lo2f(p.x); a[1] += hi2f(p.x);
    a[2] += lo2f(p.y); a[3] += hi2f(p.y);
    a[4] += lo2f(p.z); a[5] += hi2f(p.z);
    a[6] += lo2f(p.w); a[7] += hi2f(p.w);
}

template<typename IT, int MODE, int OB>
__global__ __launch_bounds__(256)
void k_aggT(const u32* __restrict__ tab,
            const int* __restrict__ row_ptr, const IT* __restrict__ sorted_src,
            const float* __restrict__ invdeg,
            void* __restrict__ oE, void* __restrict__ oB, void* __restrict__ oS,
            int n_rows){
    const int NPB = 64*NPG;
    int xcd = blockIdx.x & 7;
    int idx = blockIdx.x >> 3;
    size_t sstride = (size_t)n_rows * 16;      // u32 per shard

    const u32* shard; void* dvp; int nodebase, hi, colbase; bool leaky;
    if (MODE == 0){
        shard = tab + (size_t)xcd * sstride;   // eb shard 0..7
        dvp = (xcd < 4) ? oE : oB;
        leaky = (xcd < 4);
        colbase = (xcd & 3) * 32;
        nodebase = idx * NPB; hi = n_rows;
        if (nodebase >= hi) return;
    } else {
        int half = xcd >> 2, c = xcd & 3;      // s shard 0..3, node half
        int lo  = (int)(((long long)n_rows * half) >> 1);
        int hi2 = (int)(((long long)n_rows * (half+1)) >> 1);
        shard = tab + (size_t)c * sstride;
        dvp = oS; leaky = false;
        colbase = c * 32;
        nodebase = lo + idx*NPB; hi = hi2;
        if (nodebase >= hi) return;
    }

    int grp = threadIdx.x >> 2;                // 0..63, one node per group
    int l4  = threadIdx.x & 3;                 // 16B column slice
    const u32* tbl = shard + l4*4;

    #pragma unroll
    for (int k = 0; k < NPG; k++){
        int v = nodebase + k*64 + grp;         // consecutive groups -> consec nodes
        if (v >= hi) continue;
        int beg = row_ptr[v], end = row_ptr[v+1];
        int cnt = end - beg;
        float a[8];
        #pragma unroll
        for (int i = 0; i < 8; i++) a[i] = 0.f;

        int nq = cnt >> 2;
        int p = beg;
        int j0 = 0, j1 = 0, j2 = 0, j3 = 0;
        if (nq > 0){
            j0 = (int)sorted_src[p]; j1 = (int)sorted_src[p+1];
            j2 = (int)sorted_src[p+2]; j3 = (int)sorted_src[p+3];
        }
        for (int q = 0; q < nq; q++){
            uint4 c0 = *(const uint4*)(tbl + (size_t)j0*16);
            uint4 c1 = *(const uint4*)(tbl + (size_t)j1*16);
            uint4 c2 = *(const uint4*)(tbl + (size_t)j2*16);
            uint4 c3 = *(const uint4*)(tbl + (size_t)j3*16);
            p += 4;
            if (q + 1 < nq){                   // prefetch next quad's indices
                j0 = (int)sorted_src[p];
                j1 = (int)sorted_src[p+1];
                j2 = (int)sorted_src[p+2];
                j3 = (int)sorted_src[p+3];
            }
            acc8(a, c0); acc8(a, c1); acc8(a, c2); acc8(a, c3);
        }
        for (int r = 0; r < (cnt & 3); r++){
            int j = (int)sorted_src[p + r];
            uint4 c0 = *(const uint4*)(tbl + (size_t)j*16);
            acc8(a, c0);
        }

        float inv = invdeg[v];
        float o[8];
        #pragma unroll
        for (int i = 0; i < 8; i++){
            float x = a[i]*inv;
            o[i] = (leaky && x < 0.f) ? 0.2f*x : x;
        }
        if (OB){
            u16* dest = (u16*)dvp;
            u32 w0 = (u32)f2bf(o[0]) | ((u32)f2bf(o[1]) << 16);
            u32 w1 = (u32)f2bf(o[2]) | ((u32)f2bf(o[3]) << 16);
            u32 w2 = (u32)f2bf(o[4]) | ((u32)f2bf(o[5]) << 16);
            u32 w3 = (u32)f2bf(o[6]) | ((u32)f2bf(o[7]) << 16);
            u32x4v st = {w0, w1, w2, w3};
            __builtin_nontemporal_store(st, (u32x4v*)(dest + (size_t)v*DD + colbase + l4*8));
        } else {
            float* dest = (float*)dvp;
            f32x4 o0 = {o[0],o[1],o[2],o[3]};
            f32x4 o1 = {o[4],o[5],o[6],o[7]};
            f32x4* dp = (f32x4*)(dest + (size_t)v*DD + colbase + l4*8);
            __builtin_nontemporal_store(o0, dp);
            __builtin_nontemporal_store(o1, dp+1);
        }
    }
}

// ---------------- final-layer b/s epilogues (expmap0 / l2norm) ----------------
__global__ __launch_bounds__(256)
void k_final(const float* __restrict__ tb, const float* __restrict__ ts,
             float* __restrict__ ob, float* __restrict__ os,
             int n_rows, const float* __restrict__ cptr){
    int wid = (blockIdx.x*256 + threadIdx.x) >> 6;
    if (wid >= n_rows) return;
    int lane = threadIdx.x & 63;
    float2 vb = *(const float2*)(tb + (size_t)wid*DD + lane*2);
    float2 vs = *(const float2*)(ts + (size_t)wid*DD + lane*2);
    float ssb = vb.x*vb.x + vb.y*vb.y;
    float sss = vs.x*vs.x + vs.y*vs.y;
    #pragma unroll
    for (int m = 32; m > 0; m >>= 1){
        ssb += __shfl_xor(ssb, m, 64);
        sss += __shfl_xor(sss, m, 64);
    }
    float cc = cptr[0];
    cc = (cc > 0.f && cc < 1e30f) ? cc : 1.0f;
    float sc = sqrtf(cc);
    float nb = fmaxf(sqrtf(ssb), 1e-10f);
    float scb = tanhf(sc*nb*0.5f) / (sc*nb);
    float scs = 1.0f / fmaxf(sqrtf(sss), 1e-12f);
    *(float2*)(ob + (size_t)wid*DD + lane*2) = make_float2(vb.x*scb, vb.y*scb);
    *(float2*)(os + (size_t)wid*DD + lane*2) = make_float2(vs.x*scs, vs.y*scs);
}

extern "C" void kernel_launch(void* const* d_in, const int* in_sizes, int n_in,
                              void* d_out, int out_size, void* d_ws, size_t ws_size,
                              hipStream_t stream){
    const int*   src = (const int*)d_in[0];
    const int*   dst = (const int*)d_in[1];
    const float* emb_in[3] = {(const float*)d_in[2], (const float*)d_in[3], (const float*)d_in[4]};
    const float* W_in[3]   = {(const float*)d_in[5], (const float*)d_in[7], (const float*)d_in[9]};
    const float* b_in[3]   = {(const float*)d_in[6], (const float*)d_in[8], (const float*)d_in[10]};
    const float* b_c       = (const float*)d_in[11];

    const int E  = in_sizes[0];
    const int ND = in_sizes[2];
    const int N  = ND / DD;
    const int Lnum = in_sizes[5] / (DD*DD);
    const int nw = Lnum*DD*DD;
    const int nchunks = (N + 511) / 512;
    const bool small_idx = (N <= 65535);

    char* w = (char*)d_ws;
    auto alloc = [&](size_t bytes)->char*{
        char* p = w; w += (bytes + 255) & ~(size_t)255; return p;
    };
    u32*   ebS       = (u32*)  alloc((size_t)ND*4);     // 8 shards [N][64B] (e|b)
    u32*   sS        = (u32*)  alloc((size_t)ND*2);     // 4 shards [N][64B] (s)
    float* tb        = (float*)alloc((size_t)ND*4);     // final-layer raw means
    float* ts        = (float*)alloc((size_t)ND*4);
    u16*   xs16      = (u16*)  alloc((size_t)ND*2);     // bf16 intermediate (s)
    u16*   xe16      = (u16*)tb;                        // bf16 intermediates alias
    u16*   xb16      = (u16*)ts;                        //  tb/ts (dead until last layer)
    u16*   Wb[3];
    for (int i = 0; i < 3; i++) Wb[i] = (u16*)alloc((size_t)nw*2);
    float* invdeg    = (float*)alloc((size_t)N*4);
    int*   deg       = (int*)  alloc((size_t)N*4);
    int*   row_ptr   = (int*)  alloc((size_t)(N+1)*4);
    int*   cursor    = (int*)  alloc((size_t)N*4);
    int*   csum      = (int*)  alloc((size_t)nchunks*4);
    void*  sorted_src= (void*) alloc((size_t)E*4);
    (void)ws_size; (void)n_in; (void)out_size;

    float* out_e = (float*)d_out;
    float* out_b = out_e + ND;
    float* out_s = out_e + 2*ND;

    hipMemsetAsync(deg, 0, (size_t)N*4, stream);

    const int TB = 256;
    k_w2b3<<<dim3((nw+TB-1)/TB, 3), TB, 0, stream>>>(W_in[0], W_in[1], W_in[2],
                                                     Wb[0], Wb[1], Wb[2], nw);
    k_hist<<<(E+TB-1)/TB, TB, 0, stream>>>(dst, deg, E);
    k_chunksum<<<nchunks, 256, 0, stream>>>(deg, csum, invdeg, N);
    k_scanchunks<<<1, 256, 0, stream>>>(csum, nchunks, row_ptr, N);
    k_scanwithin<<<nchunks, 256, 0, stream>>>(deg, csum, row_ptr, cursor, N);
    if (small_idx)
        k_fill<u16><<<(E+TB-1)/TB, TB, 0, stream>>>(src, dst, cursor, (u16*)sorted_src, E);
    else
        k_fill<int><<<(E+TB-1)/TB, TB, 0, stream>>>(src, dst, cursor, (int*)sorted_src, E);

    const int gemmblocks = (N + 127) / 128;
    const int NPB = 64*NPG;
    const int nbE = (N + NPB - 1) / NPB;
    const int nbS = (((N + 1) / 2) + NPB - 1) / NPB;
    const int finblocks = (N + 3) / 4;

    for (int l = 0; l < Lnum; l++){
        bool last = (l == Lnum - 1);
        if (l == 0)
            k_gemm3<<<dim3(gemmblocks, 3), 256, 0, stream>>>(
                emb_in[0], emb_in[1], emb_in[2],
                Wb[0], Wb[1], Wb[2],
                b_in[0], b_in[1], b_in[2],
                (u16*)ebS, (u16*)sS, N, b_c);
        else
            k_gemm3b<<<dim3(gemmblocks, 3), 256, 0, stream>>>(
                xe16, xb16, xs16,
                Wb[0] + (size_t)l*DD*DD, Wb[1] + (size_t)l*DD*DD, Wb[2] + (size_t)l*DD*DD,
                b_in[0] + (size_t)l*DD,  b_in[1] + (size_t)l*DD,  b_in[2] + (size_t)l*DD,
                (u16*)ebS, (u16*)sS, N);

        void *dE, *dB, *dS;
        if (last){ dE = out_e; dB = tb;   dS = ts;   }
        else     { dE = xe16;  dB = xb16; dS = xs16; }

        if (small_idx){
            if (last){
                k_aggT<u16,0,0><<<8*nbE, 256, 0, stream>>>(ebS, row_ptr, (const u16*)sorted_src,
                                                           invdeg, dE, dB, dS, N);
                k_aggT<u16,1,0><<<8*nbS, 256, 0, stream>>>(sS,  row_ptr, (const u16*)sorted_src,
                                                           invdeg, dE, dB, dS, N);
            } else {
                k_aggT<u16,0,1><<<8*nbE, 256, 0, stream>>>(ebS, row_ptr, (const u16*)sorted_src,
                                                           invdeg, dE, dB, dS, N);
                k_aggT<u16,1,1><<<8*nbS, 256, 0, stream>>>(sS,  row_ptr, (const u16*)sorted_src,
                                                           invdeg, dE, dB, dS, N);
            }
        } else {
            if (last){
                k_aggT<int,0,0><<<8*nbE, 256, 0, stream>>>(ebS, row_ptr, (const int*)sorted_src,
                                                           invdeg, dE, dB, dS, N);
                k_aggT<int,1,0><<<8*nbS, 256, 0, stream>>>(sS,  row_ptr, (const int*)sorted_src,
                                                           invdeg, dE, dB, dS, N);
            } else {
                k_aggT<int,0,1><<<8*nbE, 256, 0, stream>>>(ebS, row_ptr, (const int*)sorted_src,
                                                           invdeg, dE, dB, dS, N);
                k_aggT<int,1,1><<<8*nbS, 256, 0, stream>>>(sS,  row_ptr, (const int*)sorted_src,
                                                           invdeg, dE, dB, dS, N);
            }
        }
        if (last)
            k_final<<<finblocks, 256, 0, stream>>>(tb, ts, out_b, out_s, N, b_c);
    }
}